// Round 7
// baseline (404.711 us; speedup 1.0000x reference)
//
#include <hip/hip_runtime.h>

#define N_NODES 50000
#define N_EDGES 800000
#define D_IN 96
#define HID 128
#define NB 391              // buckets of 128 nodes
#define BCAP 3072

typedef __attribute__((ext_vector_type(8))) _Float16 halfx8;
typedef __attribute__((ext_vector_type(2))) _Float16 half2v;
typedef __attribute__((ext_vector_type(16))) float f32x16;

// ---------------------------------------------------------------------------
// CSR build via LDS-binned counting sort (unchanged from round 6).
// ---------------------------------------------------------------------------
__global__ __launch_bounds__(256) void bucket_hist_kernel(const int* __restrict__ dst,
                                                          int* __restrict__ bhist) {
    __shared__ int lh[NB];
    int t = threadIdx.x;
    for (int i = t; i < NB; i += 256) lh[i] = 0;
    __syncthreads();
    int base = blockIdx.x * 4096;
#pragma unroll
    for (int i = 0; i < 16; i++) {
        int e = base + i * 256 + t;
        if (e < N_EDGES) atomicAdd(&lh[dst[e] >> 7], 1);
    }
    __syncthreads();
    for (int i = t; i < NB; i += 256) atomicAdd(&bhist[i], lh[i]);
}

__global__ __launch_bounds__(512) void scan_buckets_kernel(const int* __restrict__ bhist,
                                                           int* __restrict__ boff,
                                                           int* __restrict__ bcursor) {
    __shared__ int s[512];
    int t = threadIdx.x;
    int v = (t < NB) ? bhist[t] : 0;
    s[t] = v;
    __syncthreads();
    for (int off = 1; off < 512; off <<= 1) {
        int u = (t >= off) ? s[t - off] : 0;
        __syncthreads();
        s[t] += u;
        __syncthreads();
    }
    if (t < NB) {
        int ex = s[t] - v;
        boff[t] = ex;
        bcursor[t] = ex;
    }
    if (t == NB - 1) boff[NB] = s[t];
}

__global__ __launch_bounds__(512) void bin_kernel(const int* __restrict__ src,
                                                  const int* __restrict__ dst,
                                                  int* __restrict__ bcursor,
                                                  unsigned long long* __restrict__ binned) {
    __shared__ int lh[NB];
    __shared__ int gbs[NB];
    int t = threadIdx.x;
    for (int i = t; i < NB; i += 512) lh[i] = 0;
    __syncthreads();
    int base = blockIdx.x * 8192;
    unsigned long long pk[16];
    int bb[16], rk[16];
#pragma unroll
    for (int i = 0; i < 16; i++) {
        int e = base + i * 512 + t;
        bb[i] = -1;
        if (e < N_EDGES) {
            int s = src[e], d = dst[e];
            int b = d >> 7;
            bb[i] = b;
            pk[i] = ((unsigned long long)s << 27) |
                    ((unsigned long long)(d & 127) << 20) | (unsigned long long)e;
            rk[i] = atomicAdd(&lh[b], 1);
        }
    }
    __syncthreads();
    for (int i = t; i < NB; i += 512) gbs[i] = atomicAdd(&bcursor[i], lh[i]);
    __syncthreads();
#pragma unroll
    for (int i = 0; i < 16; i++) {
        if (bb[i] >= 0) binned[gbs[bb[i]] + rk[i]] = pk[i];
    }
}

__global__ __launch_bounds__(256) void bucket_sort_kernel(const unsigned long long* __restrict__ binned,
                                                          const int* __restrict__ boff,
                                                          int2* __restrict__ ce_se,
                                                          int* __restrict__ ce_dst,
                                                          int* __restrict__ csr_ptr,
                                                          float* __restrict__ dinv) {
    __shared__ unsigned long long ed[BCAP];
    __shared__ int2 sorted[BCAP];
    __shared__ int cntA[128], sc[128];
    int b = blockIdx.x;
    int t = threadIdx.x;
    int base = boff[b];
    int k = boff[b + 1] - base;
    if (k > BCAP) k = BCAP;
    if (t < 128) cntA[t] = 0;
    __syncthreads();
    int rk[12], li[12];
    int nmine = 0;
    for (int i = t; i < k; i += 256) {
        unsigned long long p = binned[base + i];
        ed[i] = p;
        int d = (int)((p >> 20) & 127);
        rk[nmine] = atomicAdd(&cntA[d], 1);
        li[nmine] = i;
        nmine++;
    }
    __syncthreads();
    if (t < 128) sc[t] = cntA[t];
    __syncthreads();
    for (int off = 1; off < 128; off <<= 1) {
        int u = 0;
        if (t < 128 && t >= off) u = sc[t - off];
        __syncthreads();
        if (t < 128) sc[t] += u;
        __syncthreads();
    }
    for (int m = 0; m < nmine; m++) {
        unsigned long long p = ed[li[m]];
        int d = (int)((p >> 20) & 127);
        int pos = sc[d] - cntA[d] + rk[m];
        int srcn = (int)(p >> 27);
        int eid = (int)(p & 0xFFFFF);
        sorted[pos] = make_int2(srcn | (d << 16), eid);
    }
    __syncthreads();
    for (int i = t; i < k; i += 256) {
        int2 se = sorted[i];
        ce_se[base + i] = make_int2(se.x & 0xFFFF, se.y);
        ce_dst[base + i] = (b << 7) + (se.x >> 16);
    }
    if (t < 128) {
        int node = (b << 7) + t;
        if (node < N_NODES) {
            csr_ptr[node] = base + sc[t] - cntA[t];
            dinv[node] = 1.0f / sqrtf((float)(cntA[t] + 1));
        }
    }
    if (b == NB - 1 && t == 0) csr_ptr[N_NODES] = boff[NB];
}

// ---------------------------------------------------------------------------
// Pack weights into MFMA B-fragment order (fp16). Unchanged.
// ---------------------------------------------------------------------------
__global__ __launch_bounds__(256) void pack_weights_kernel(const float* __restrict__ W_in,
                                                           const float* __restrict__ W1,
                                                           const float* __restrict__ W2,
                                                           const float* __restrict__ Wm1,
                                                           _Float16* __restrict__ packed) {
    int t = blockIdx.x * 256 + threadIdx.x;
    const float* Wsrc;
    int K, u;
    if (t < 12288)      { Wsrc = W_in;            K = 96;  u = t; }
    else if (t < 28672) { Wsrc = W1;              K = 128; u = t - 12288; }
    else if (t < 45056) { Wsrc = W2;              K = 128; u = t - 28672; }
    else if (t < 61440) { Wsrc = Wm1;             K = 128; u = t - 45056; }
    else                { Wsrc = Wm1 + 128 * 128; K = 128; u = t - 61440; }
    if (t >= 77824) return;
    int steps = K >> 4;
    int cb = u / (steps * 512);
    int rem = u - cb * steps * 512;
    int s = rem >> 9;
    int lane = (rem >> 3) & 63;
    int j = rem & 7;
    int k = s * 16 + ((lane >> 5) << 3) + j;
    int n = (cb << 5) + (lane & 31);
    packed[t] = (_Float16)Wsrc[k * 128 + n];
}

// ---------------------------------------------------------------------------
// Fused input: y1 = (relu(x@W_in + b_in) @ W1) * dinv[row].
// h0 lives only in LDS. x converted fp32->fp16 during staging.
// ---------------------------------------------------------------------------
__global__ __launch_bounds__(256) void fused_in_kernel(const float* __restrict__ x,
                                                       const _Float16* __restrict__ WpIn,
                                                       const _Float16* __restrict__ Wp1,
                                                       const float* __restrict__ b_in,
                                                       const float* __restrict__ dinv,
                                                       _Float16* __restrict__ y1, int M) {
    __shared__ _Float16 As[64 * 104];   // x tile fp16, stride 96+8
    __shared__ _Float16 Hs[64 * 136];   // h0 tile, stride 128+8
    int tid = threadIdx.x;
    int M0 = blockIdx.x * 64;
    // stage x (fp32 -> fp16), 64 rows x 24 float4 chunks
    for (int i = tid; i < 64 * 24; i += 256) {
        int r = i / 24, c = i - r * 24;
        float4 v = make_float4(0.f, 0.f, 0.f, 0.f);
        int row = M0 + r;
        if (row < M) v = *(const float4*)&x[(size_t)row * 96 + c * 4];
        half2v a = {(_Float16)v.x, (_Float16)v.y};
        half2v b = {(_Float16)v.z, (_Float16)v.w};
        *(half2v*)&As[r * 104 + c * 4] = a;
        *(half2v*)&As[r * 104 + c * 4 + 2] = b;
    }
    __syncthreads();

    int wave = tid >> 6, lane = tid & 63;
    int rb = wave & 1;
    int cb0 = (wave >> 1) * 2;
    int colA = cb0 * 32 + (lane & 31);
    int colB = colA + 32;
    // phase 1: h0 = relu(x@W_in + b_in) -> Hs
    {
        const halfx8* bp0 = (const halfx8*)WpIn + (size_t)cb0 * 6 * 64 + lane;
        const halfx8* bp1 = bp0 + (size_t)6 * 64;
        const _Float16* arow = &As[(rb * 32 + (lane & 31)) * 104 + ((lane >> 5) << 3)];
        f32x16 acc0 = {}, acc1 = {};
#pragma unroll
        for (int s = 0; s < 6; s++) {
            halfx8 a = *(const halfx8*)&arow[s * 16];
            acc0 = __builtin_amdgcn_mfma_f32_32x32x16_f16(a, bp0[s * 64], acc0, 0, 0, 0);
            acc1 = __builtin_amdgcn_mfma_f32_32x32x16_f16(a, bp1[s * 64], acc1, 0, 0, 0);
        }
        float bA = b_in[colA], bB = b_in[colB];
#pragma unroll
        for (int r = 0; r < 16; r++) {
            int rl = (r & 3) + 8 * (r >> 2) + 4 * (lane >> 5);
            int lrow = rb * 32 + rl;
            Hs[lrow * 136 + colA] = (_Float16)fmaxf(acc0[r] + bA, 0.f);
            Hs[lrow * 136 + colB] = (_Float16)fmaxf(acc1[r] + bB, 0.f);
        }
    }
    __syncthreads();
    // phase 2: y1 = (h0 @ W1) * dinv
    {
        const halfx8* bp0 = (const halfx8*)Wp1 + (size_t)cb0 * 8 * 64 + lane;
        const halfx8* bp1 = bp0 + (size_t)8 * 64;
        const _Float16* arow = &Hs[(rb * 32 + (lane & 31)) * 136 + ((lane >> 5) << 3)];
        f32x16 acc0 = {}, acc1 = {};
#pragma unroll
        for (int s = 0; s < 8; s++) {
            halfx8 a = *(const halfx8*)&arow[s * 16];
            acc0 = __builtin_amdgcn_mfma_f32_32x32x16_f16(a, bp0[s * 64], acc0, 0, 0, 0);
            acc1 = __builtin_amdgcn_mfma_f32_32x32x16_f16(a, bp1[s * 64], acc1, 0, 0, 0);
        }
#pragma unroll
        for (int r = 0; r < 16; r++) {
            int rl = (r & 3) + 8 * (r >> 2) + 4 * (lane >> 5);
            int grow = M0 + rb * 32 + rl;
            if (grow < M) {
                float sc = dinv[grow];
                y1[(size_t)grow * 128 + colA] = (_Float16)(acc0[r] * sc);
                y1[(size_t)grow * 128 + colB] = (_Float16)(acc1[r] * sc);
            }
        }
    }
}

// ---------------------------------------------------------------------------
// Fused aggregate + GEMM: h = relu(dinv*(y_self + sum y[src]) + aggbias) in LDS,
// then outA = (h@WpA + biasA) * (useRS ? dinv : 1); optionally outB = h@WpB.
// ---------------------------------------------------------------------------
__global__ __launch_bounds__(256) void fused_agg_gemm_kernel(
    const _Float16* __restrict__ y, const float* __restrict__ dinv,
    const int* __restrict__ ptr, const int2* __restrict__ ce_se,
    const float* __restrict__ aggbias,
    const _Float16* __restrict__ WpA, const float* __restrict__ biasA, int useRS,
    const _Float16* __restrict__ WpB,
    _Float16* __restrict__ outA, _Float16* __restrict__ outB, int M) {
    __shared__ _Float16 Hs[64 * 136];
    int tid = threadIdx.x;
    int M0 = blockIdx.x * 64;
    int wave = tid >> 6, lane = tid & 63;
    int c = lane * 2;
    float2 bv = *(const float2*)&aggbias[c];

    // --- aggregation phase: 16 passes x 4 waves = 64 nodes ---
    for (int pass = 0; pass < 16; pass++) {
        int ln = pass * 4 + wave;
        int node = M0 + ln;
        float o0 = 0.f, o1 = 0.f;
        if (node < M) {
            float di = dinv[node];
            half2v self = ((const half2v*)&y[(size_t)node * 128])[lane];
            float a0 = (float)self.x, a1 = (float)self.y;
            float b0 = 0.f, b1 = 0.f, c0 = 0.f, c1 = 0.f, d0 = 0.f, d1 = 0.f;
            int s0 = ptr[node], s1 = ptr[node + 1];
            int j = s0;
            for (; j + 7 < s1; j += 8) {
                int n0 = ce_se[j].x, n1 = ce_se[j + 1].x, n2 = ce_se[j + 2].x, n3 = ce_se[j + 3].x;
                int n4 = ce_se[j + 4].x, n5 = ce_se[j + 5].x, n6 = ce_se[j + 6].x, n7 = ce_se[j + 7].x;
                half2v v0 = ((const half2v*)&y[(size_t)n0 * 128])[lane];
                half2v v1 = ((const half2v*)&y[(size_t)n1 * 128])[lane];
                half2v v2 = ((const half2v*)&y[(size_t)n2 * 128])[lane];
                half2v v3 = ((const half2v*)&y[(size_t)n3 * 128])[lane];
                half2v v4 = ((const half2v*)&y[(size_t)n4 * 128])[lane];
                half2v v5 = ((const half2v*)&y[(size_t)n5 * 128])[lane];
                half2v v6 = ((const half2v*)&y[(size_t)n6 * 128])[lane];
                half2v v7 = ((const half2v*)&y[(size_t)n7 * 128])[lane];
                a0 += (float)v0.x + (float)v4.x; a1 += (float)v0.y + (float)v4.y;
                b0 += (float)v1.x + (float)v5.x; b1 += (float)v1.y + (float)v5.y;
                c0 += (float)v2.x + (float)v6.x; c1 += (float)v2.y + (float)v6.y;
                d0 += (float)v3.x + (float)v7.x; d1 += (float)v3.y + (float)v7.y;
            }
            for (; j < s1; j++) {
                int n = ce_se[j].x;
                half2v v = ((const half2v*)&y[(size_t)n * 128])[lane];
                a0 += (float)v.x; a1 += (float)v.y;
            }
            o0 = fmaxf(di * (a0 + b0 + c0 + d0) + bv.x, 0.f);
            o1 = fmaxf(di * (a1 + b1 + c1 + d1) + bv.y, 0.f);
        }
        half2v ov = {(_Float16)o0, (_Float16)o1};
        *(half2v*)&Hs[ln * 136 + c] = ov;
    }
    __syncthreads();

    // --- GEMM phase ---
    int rb = wave & 1;
    int cb0 = (wave >> 1) * 2;
    int colA = cb0 * 32 + (lane & 31);
    int colB = colA + 32;
    const _Float16* arow = &Hs[(rb * 32 + (lane & 31)) * 136 + ((lane >> 5) << 3)];
    const halfx8* ba0 = (const halfx8*)WpA + (size_t)cb0 * 8 * 64 + lane;
    const halfx8* ba1 = ba0 + (size_t)8 * 64;
    f32x16 aa0 = {}, aa1 = {};
    if (outB) {
        const halfx8* bb0 = (const halfx8*)WpB + (size_t)cb0 * 8 * 64 + lane;
        const halfx8* bb1 = bb0 + (size_t)8 * 64;
        f32x16 ab0 = {}, ab1 = {};
#pragma unroll
        for (int s = 0; s < 8; s++) {
            halfx8 a = *(const halfx8*)&arow[s * 16];
            aa0 = __builtin_amdgcn_mfma_f32_32x32x16_f16(a, ba0[s * 64], aa0, 0, 0, 0);
            aa1 = __builtin_amdgcn_mfma_f32_32x32x16_f16(a, ba1[s * 64], aa1, 0, 0, 0);
            ab0 = __builtin_amdgcn_mfma_f32_32x32x16_f16(a, bb0[s * 64], ab0, 0, 0, 0);
            ab1 = __builtin_amdgcn_mfma_f32_32x32x16_f16(a, bb1[s * 64], ab1, 0, 0, 0);
        }
        float bA = biasA ? biasA[colA] : 0.f;
        float bB = biasA ? biasA[colB] : 0.f;
#pragma unroll
        for (int r = 0; r < 16; r++) {
            int rl = (r & 3) + 8 * (r >> 2) + 4 * (lane >> 5);
            int grow = M0 + rb * 32 + rl;
            if (grow < M) {
                outA[(size_t)grow * 128 + colA] = (_Float16)(aa0[r] + bA);
                outA[(size_t)grow * 128 + colB] = (_Float16)(aa1[r] + bB);
                outB[(size_t)grow * 128 + colA] = (_Float16)ab0[r];
                outB[(size_t)grow * 128 + colB] = (_Float16)ab1[r];
            }
        }
    } else {
#pragma unroll
        for (int s = 0; s < 8; s++) {
            halfx8 a = *(const halfx8*)&arow[s * 16];
            aa0 = __builtin_amdgcn_mfma_f32_32x32x16_f16(a, ba0[s * 64], aa0, 0, 0, 0);
            aa1 = __builtin_amdgcn_mfma_f32_32x32x16_f16(a, ba1[s * 64], aa1, 0, 0, 0);
        }
        float bA = biasA ? biasA[colA] : 0.f;
        float bB = biasA ? biasA[colB] : 0.f;
#pragma unroll
        for (int r = 0; r < 16; r++) {
            int rl = (r & 3) + 8 * (r >> 2) + 4 * (lane >> 5);
            int grow = M0 + rb * 32 + rl;
            if (grow < M) {
                float sc = useRS ? dinv[grow] : 1.f;
                outA[(size_t)grow * 128 + colA] = (_Float16)((aa0[r] + bA) * sc);
                outA[(size_t)grow * 128 + colB] = (_Float16)((aa1[r] + bB) * sc);
            }
        }
    }
}

// ---------------------------------------------------------------------------
// Edge MLP: 64 edges/block, 4 edges per 16-lane group (8 gathers in flight).
// ---------------------------------------------------------------------------
__global__ __launch_bounds__(256) void edge_mlp_kernel(const _Float16* __restrict__ Ub,
                                                       const _Float16* __restrict__ Vb,
                                                       const int2* __restrict__ ce_se,
                                                       const int* __restrict__ ce_dst,
                                                       const float* __restrict__ Wm2,
                                                       const float* __restrict__ bm2,
                                                       float* __restrict__ out) {
    __shared__ int ssrc[64], sdst[64], seid[64];
    int tid = threadIdx.x;
    int e0 = blockIdx.x * 64;
    if (tid < 64) {
        int2 se = ce_se[e0 + tid];
        ssrc[tid] = se.x;
        seid[tid] = se.y;
    } else if (tid < 128) {
        sdst[tid - 64] = ce_dst[e0 + tid - 64];
    }
    __syncthreads();
    int g = tid >> 4;
    int l = tid & 15;
    int ga = g, gb = g + 16, gc = g + 32, gd = g + 48;
    halfx8 u0 = *(const halfx8*)&Ub[(size_t)ssrc[ga] * 128 + l * 8];
    halfx8 v0 = *(const halfx8*)&Vb[(size_t)sdst[ga] * 128 + l * 8];
    halfx8 u1 = *(const halfx8*)&Ub[(size_t)ssrc[gb] * 128 + l * 8];
    halfx8 v1 = *(const halfx8*)&Vb[(size_t)sdst[gb] * 128 + l * 8];
    halfx8 u2 = *(const halfx8*)&Ub[(size_t)ssrc[gc] * 128 + l * 8];
    halfx8 v2 = *(const halfx8*)&Vb[(size_t)sdst[gc] * 128 + l * 8];
    halfx8 u3 = *(const halfx8*)&Ub[(size_t)ssrc[gd] * 128 + l * 8];
    halfx8 v3 = *(const halfx8*)&Vb[(size_t)sdst[gd] * 128 + l * 8];
    float4 w0 = *(const float4*)&Wm2[l * 8];
    float4 w1 = *(const float4*)&Wm2[l * 8 + 4];
    float wm[8] = {w0.x, w0.y, w0.z, w0.w, w1.x, w1.y, w1.z, w1.w};
    float p0 = 0.f, p1 = 0.f, p2 = 0.f, p3 = 0.f;
#pragma unroll
    for (int t = 0; t < 8; t++) {
        p0 = fmaf(fmaxf((float)u0[t] + (float)v0[t], 0.f), wm[t], p0);
        p1 = fmaf(fmaxf((float)u1[t] + (float)v1[t], 0.f), wm[t], p1);
        p2 = fmaf(fmaxf((float)u2[t] + (float)v2[t], 0.f), wm[t], p2);
        p3 = fmaf(fmaxf((float)u3[t] + (float)v3[t], 0.f), wm[t], p3);
    }
#pragma unroll
    for (int d = 1; d < 16; d <<= 1) {
        p0 += __shfl_xor(p0, d);
        p1 += __shfl_xor(p1, d);
        p2 += __shfl_xor(p2, d);
        p3 += __shfl_xor(p3, d);
    }
    if (l == 0) {
        float bb = bm2[0];
        out[seid[ga]] = p0 + bb;
        out[seid[gb]] = p1 + bb;
        out[seid[gc]] = p2 + bb;
        out[seid[gd]] = p3 + bb;
    }
}

// ---------------------------------------------------------------------------
extern "C" void kernel_launch(void* const* d_in, const int* in_sizes, int n_in,
                              void* d_out, int out_size, void* d_ws, size_t ws_size,
                              hipStream_t stream) {
    const float* x    = (const float*)d_in[0];
    const int* eidx   = (const int*)d_in[1];
    const float* W_in = (const float*)d_in[2];
    const float* b_in = (const float*)d_in[3];
    const float* W1   = (const float*)d_in[4];
    const float* b1   = (const float*)d_in[5];
    const float* W2   = (const float*)d_in[6];
    const float* b2   = (const float*)d_in[7];
    const float* Wm1  = (const float*)d_in[8];
    const float* bm1  = (const float*)d_in[9];
    const float* Wm2  = (const float*)d_in[10];
    const float* bm2  = (const float*)d_in[11];
    float* out = (float*)d_out;
    const int* src = eidx;
    const int* dst = eidx + N_EDGES;

    char* w = (char*)d_ws;
    size_t off = 0;
    auto alloc = [&](size_t bytes) -> char* {
        char* p = w + off;
        off = (off + bytes + 255) & ~(size_t)255;
        return p;
    };
    int* bhist    = (int*)alloc((size_t)NB * 4);
    int* boff     = (int*)alloc((size_t)(NB + 1) * 4);
    int* bcursor  = (int*)alloc((size_t)NB * 4);
    int* csr_ptr  = (int*)alloc((size_t)(N_NODES + 1) * 4);
    float* dinv   = (float*)alloc((size_t)N_NODES * 4);
    unsigned long long* binned = (unsigned long long*)alloc((size_t)N_EDGES * 8);
    int2* ce_se   = (int2*)alloc((size_t)N_EDGES * 8);
    int* ce_dst   = (int*)alloc((size_t)N_EDGES * 4);
    _Float16* Wp  = (_Float16*)alloc((size_t)77824 * 2);
    _Float16* y1  = (_Float16*)alloc((size_t)N_NODES * HID * 2);
    _Float16* y2  = (_Float16*)alloc((size_t)N_NODES * HID * 2);
    _Float16* Ub  = (_Float16*)alloc((size_t)N_NODES * HID * 2);
    _Float16* Vb  = (_Float16*)alloc((size_t)N_NODES * HID * 2);

    const _Float16* WpIn  = Wp;              // K=96, steps 6
    const _Float16* Wp1   = Wp + 12288;      // K=128
    const _Float16* Wp2   = Wp + 28672;
    const _Float16* WpM1a = Wp + 45056;
    const _Float16* WpM1b = Wp + 61440;

    // CSR build (counting sort)
    hipMemsetAsync(bhist, 0, (size_t)NB * 4, stream);
    bucket_hist_kernel<<<196, 256, 0, stream>>>(dst, bhist);
    scan_buckets_kernel<<<1, 512, 0, stream>>>(bhist, boff, bcursor);
    bin_kernel<<<98, 512, 0, stream>>>(src, dst, bcursor, binned);
    bucket_sort_kernel<<<NB, 256, 0, stream>>>(binned, boff, ce_se, ce_dst, csr_ptr, dinv);
    pack_weights_kernel<<<(77824 + 255) / 256, 256, 0, stream>>>(W_in, W1, W2, Wm1, Wp);

    int gblocks = (N_NODES + 63) / 64;  // 782
    // y1 = (relu(x@W_in+b_in) @ W1) * dinv
    fused_in_kernel<<<gblocks, 256, 0, stream>>>(x, WpIn, Wp1, b_in, dinv, y1, N_NODES);
    // h1 = relu(agg(y1)+b1) [LDS]; y2 = (h1@W2)*dinv
    fused_agg_gemm_kernel<<<gblocks, 256, 0, stream>>>(y1, dinv, csr_ptr, ce_se, b1,
                                                       Wp2, nullptr, 1, nullptr,
                                                       y2, nullptr, N_NODES);
    // h2 = relu(agg(y2)+b2) [LDS]; U = h2@Wm1a+bm1, V = h2@Wm1b
    fused_agg_gemm_kernel<<<gblocks, 256, 0, stream>>>(y2, dinv, csr_ptr, ce_se, b2,
                                                       WpM1a, bm1, 0, WpM1b,
                                                       Ub, Vb, N_NODES);
    // logits (CSR order, scatter by original edge id)
    edge_mlp_kernel<<<N_EDGES / 64, 256, 0, stream>>>(Ub, Vb, ce_se, ce_dst, Wm2, bm2, out);
}

// Round 8
// 277.876 us; speedup vs baseline: 1.4564x; 1.4564x over previous
//
#include <hip/hip_runtime.h>

#define N_NODES 50000
#define N_EDGES 800000
#define D_IN 96
#define HID 128
#define NB 391              // buckets of 128 nodes
#define BCAP 3072

typedef __attribute__((ext_vector_type(8))) _Float16 halfx8;
typedef __attribute__((ext_vector_type(2))) _Float16 half2v;
typedef __attribute__((ext_vector_type(16))) float f32x16;

// ---------------------------------------------------------------------------
// CSR build via LDS-binned counting sort (round-6 proven).
// ---------------------------------------------------------------------------
__global__ __launch_bounds__(256) void bucket_hist_kernel(const int* __restrict__ dst,
                                                          int* __restrict__ bhist) {
    __shared__ int lh[NB];
    int t = threadIdx.x;
    for (int i = t; i < NB; i += 256) lh[i] = 0;
    __syncthreads();
    int base = blockIdx.x * 4096;
#pragma unroll
    for (int i = 0; i < 16; i++) {
        int e = base + i * 256 + t;
        if (e < N_EDGES) atomicAdd(&lh[dst[e] >> 7], 1);
    }
    __syncthreads();
    for (int i = t; i < NB; i += 256) atomicAdd(&bhist[i], lh[i]);
}

__global__ __launch_bounds__(512) void scan_buckets_kernel(const int* __restrict__ bhist,
                                                           int* __restrict__ boff,
                                                           int* __restrict__ bcursor) {
    __shared__ int s[512];
    int t = threadIdx.x;
    int v = (t < NB) ? bhist[t] : 0;
    s[t] = v;
    __syncthreads();
    for (int off = 1; off < 512; off <<= 1) {
        int u = (t >= off) ? s[t - off] : 0;
        __syncthreads();
        s[t] += u;
        __syncthreads();
    }
    if (t < NB) {
        int ex = s[t] - v;
        boff[t] = ex;
        bcursor[t] = ex;
    }
    if (t == NB - 1) boff[NB] = s[t];
}

__global__ __launch_bounds__(512) void bin_kernel(const int* __restrict__ src,
                                                  const int* __restrict__ dst,
                                                  int* __restrict__ bcursor,
                                                  unsigned long long* __restrict__ binned) {
    __shared__ int lh[NB];
    __shared__ int gbs[NB];
    int t = threadIdx.x;
    for (int i = t; i < NB; i += 512) lh[i] = 0;
    __syncthreads();
    int base = blockIdx.x * 8192;
    unsigned long long pk[16];
    int bb[16], rk[16];
#pragma unroll
    for (int i = 0; i < 16; i++) {
        int e = base + i * 512 + t;
        bb[i] = -1;
        if (e < N_EDGES) {
            int s = src[e], d = dst[e];
            int b = d >> 7;
            bb[i] = b;
            pk[i] = ((unsigned long long)s << 27) |
                    ((unsigned long long)(d & 127) << 20) | (unsigned long long)e;
            rk[i] = atomicAdd(&lh[b], 1);
        }
    }
    __syncthreads();
    for (int i = t; i < NB; i += 512) gbs[i] = atomicAdd(&bcursor[i], lh[i]);
    __syncthreads();
#pragma unroll
    for (int i = 0; i < 16; i++) {
        if (bb[i] >= 0) binned[gbs[bb[i]] + rk[i]] = pk[i];
    }
}

__global__ __launch_bounds__(256) void bucket_sort_kernel(const unsigned long long* __restrict__ binned,
                                                          const int* __restrict__ boff,
                                                          int2* __restrict__ ce_se,
                                                          int* __restrict__ ce_dst,
                                                          int* __restrict__ csr_ptr,
                                                          float* __restrict__ dinv) {
    __shared__ unsigned long long ed[BCAP];
    __shared__ int2 sorted[BCAP];
    __shared__ int cntA[128], sc[128];
    int b = blockIdx.x;
    int t = threadIdx.x;
    int base = boff[b];
    int k = boff[b + 1] - base;
    if (k > BCAP) k = BCAP;
    if (t < 128) cntA[t] = 0;
    __syncthreads();
    int rk[12], li[12];
    int nmine = 0;
    for (int i = t; i < k; i += 256) {
        unsigned long long p = binned[base + i];
        ed[i] = p;
        int d = (int)((p >> 20) & 127);
        rk[nmine] = atomicAdd(&cntA[d], 1);
        li[nmine] = i;
        nmine++;
    }
    __syncthreads();
    if (t < 128) sc[t] = cntA[t];
    __syncthreads();
    for (int off = 1; off < 128; off <<= 1) {
        int u = 0;
        if (t < 128 && t >= off) u = sc[t - off];
        __syncthreads();
        if (t < 128) sc[t] += u;
        __syncthreads();
    }
    for (int m = 0; m < nmine; m++) {
        unsigned long long p = ed[li[m]];
        int d = (int)((p >> 20) & 127);
        int pos = sc[d] - cntA[d] + rk[m];
        int srcn = (int)(p >> 27);
        int eid = (int)(p & 0xFFFFF);
        sorted[pos] = make_int2(srcn | (d << 16), eid);
    }
    __syncthreads();
    for (int i = t; i < k; i += 256) {
        int2 se = sorted[i];
        ce_se[base + i] = make_int2(se.x & 0xFFFF, se.y);
        ce_dst[base + i] = (b << 7) + (se.x >> 16);
    }
    if (t < 128) {
        int node = (b << 7) + t;
        if (node < N_NODES) {
            csr_ptr[node] = base + sc[t] - cntA[t];
            dinv[node] = 1.0f / sqrtf((float)(cntA[t] + 1));
        }
    }
    if (b == NB - 1 && t == 0) csr_ptr[N_NODES] = boff[NB];
}

// ---------------------------------------------------------------------------
// Pack weights into MFMA B-fragment order (fp16).
// ---------------------------------------------------------------------------
__global__ __launch_bounds__(256) void pack_weights_kernel(const float* __restrict__ W_in,
                                                           const float* __restrict__ W1,
                                                           const float* __restrict__ W2,
                                                           const float* __restrict__ Wm1,
                                                           _Float16* __restrict__ packed) {
    int t = blockIdx.x * 256 + threadIdx.x;
    const float* Wsrc;
    int K, u;
    if (t < 12288)      { Wsrc = W_in;            K = 96;  u = t; }
    else if (t < 28672) { Wsrc = W1;              K = 128; u = t - 12288; }
    else if (t < 45056) { Wsrc = W2;              K = 128; u = t - 28672; }
    else if (t < 61440) { Wsrc = Wm1;             K = 128; u = t - 45056; }
    else                { Wsrc = Wm1 + 128 * 128; K = 128; u = t - 61440; }
    if (t >= 77824) return;
    int steps = K >> 4;
    int cb = u / (steps * 512);
    int rem = u - cb * steps * 512;
    int s = rem >> 9;
    int lane = (rem >> 3) & 63;
    int j = rem & 7;
    int k = s * 16 + ((lane >> 5) << 3) + j;
    int n = (cb << 5) + (lane & 31);
    packed[t] = (_Float16)Wsrc[k * 128 + n];
}

// ---------------------------------------------------------------------------
// Fused input: y1 = (relu(x@W_in + b_in) @ W1) * dinv[row]. h0 LDS-only.
// (MFMA-dense, no gather — fusion safe here, unlike the aggregate.)
// ---------------------------------------------------------------------------
__global__ __launch_bounds__(256) void fused_in_kernel(const float* __restrict__ x,
                                                       const _Float16* __restrict__ WpIn,
                                                       const _Float16* __restrict__ Wp1,
                                                       const float* __restrict__ b_in,
                                                       const float* __restrict__ dinv,
                                                       _Float16* __restrict__ y1, int M) {
    __shared__ _Float16 As[64 * 104];
    __shared__ _Float16 Hs[64 * 136];
    int tid = threadIdx.x;
    int M0 = blockIdx.x * 64;
    for (int i = tid; i < 64 * 24; i += 256) {
        int r = i / 24, c = i - r * 24;
        float4 v = make_float4(0.f, 0.f, 0.f, 0.f);
        int row = M0 + r;
        if (row < M) v = *(const float4*)&x[(size_t)row * 96 + c * 4];
        half2v a = {(_Float16)v.x, (_Float16)v.y};
        half2v b = {(_Float16)v.z, (_Float16)v.w};
        *(half2v*)&As[r * 104 + c * 4] = a;
        *(half2v*)&As[r * 104 + c * 4 + 2] = b;
    }
    __syncthreads();

    int wave = tid >> 6, lane = tid & 63;
    int rb = wave & 1;
    int cb0 = (wave >> 1) * 2;
    int colA = cb0 * 32 + (lane & 31);
    int colB = colA + 32;
    {
        const halfx8* bp0 = (const halfx8*)WpIn + (size_t)cb0 * 6 * 64 + lane;
        const halfx8* bp1 = bp0 + (size_t)6 * 64;
        const _Float16* arow = &As[(rb * 32 + (lane & 31)) * 104 + ((lane >> 5) << 3)];
        f32x16 acc0 = {}, acc1 = {};
#pragma unroll
        for (int s = 0; s < 6; s++) {
            halfx8 a = *(const halfx8*)&arow[s * 16];
            acc0 = __builtin_amdgcn_mfma_f32_32x32x16_f16(a, bp0[s * 64], acc0, 0, 0, 0);
            acc1 = __builtin_amdgcn_mfma_f32_32x32x16_f16(a, bp1[s * 64], acc1, 0, 0, 0);
        }
        float bA = b_in[colA], bB = b_in[colB];
#pragma unroll
        for (int r = 0; r < 16; r++) {
            int rl = (r & 3) + 8 * (r >> 2) + 4 * (lane >> 5);
            int lrow = rb * 32 + rl;
            Hs[lrow * 136 + colA] = (_Float16)fmaxf(acc0[r] + bA, 0.f);
            Hs[lrow * 136 + colB] = (_Float16)fmaxf(acc1[r] + bB, 0.f);
        }
    }
    __syncthreads();
    {
        const halfx8* bp0 = (const halfx8*)Wp1 + (size_t)cb0 * 8 * 64 + lane;
        const halfx8* bp1 = bp0 + (size_t)8 * 64;
        const _Float16* arow = &Hs[(rb * 32 + (lane & 31)) * 136 + ((lane >> 5) << 3)];
        f32x16 acc0 = {}, acc1 = {};
#pragma unroll
        for (int s = 0; s < 8; s++) {
            halfx8 a = *(const halfx8*)&arow[s * 16];
            acc0 = __builtin_amdgcn_mfma_f32_32x32x16_f16(a, bp0[s * 64], acc0, 0, 0, 0);
            acc1 = __builtin_amdgcn_mfma_f32_32x32x16_f16(a, bp1[s * 64], acc1, 0, 0, 0);
        }
#pragma unroll
        for (int r = 0; r < 16; r++) {
            int rl = (r & 3) + 8 * (r >> 2) + 4 * (lane >> 5);
            int grow = M0 + rb * 32 + rl;
            if (grow < M) {
                float sc = dinv[grow];
                y1[(size_t)grow * 128 + colA] = (_Float16)(acc0[r] * sc);
                y1[(size_t)grow * 128 + colB] = (_Float16)(acc1[r] * sc);
            }
        }
    }
}

// ---------------------------------------------------------------------------
// Standalone fp16 MFMA node GEMM (round-6 proven).
// ---------------------------------------------------------------------------
__global__ __launch_bounds__(256) void gemm_f16_kernel(const _Float16* __restrict__ A,
                                                       const _Float16* __restrict__ Wp,
                                                       const float* __restrict__ bias,
                                                       const float* __restrict__ rowscale,
                                                       _Float16* __restrict__ out,
                                                       int M, int K, int steps, int dorelu) {
    __shared__ _Float16 As[64 * 136];
    int tid = threadIdx.x;
    int M0 = blockIdx.x * 64;
    int stride = K + 8;
    int CH = K >> 3;
    int tot = 64 * CH;
    for (int i = tid; i < tot; i += 256) {
        int r = i / CH, c = i - r * CH;
        uint4 v = make_uint4(0, 0, 0, 0);
        int row = M0 + r;
        if (row < M) v = *(const uint4*)&A[(size_t)row * K + c * 8];
        *(uint4*)&As[r * stride + c * 8] = v;
    }
    __syncthreads();

    int wave = tid >> 6, lane = tid & 63;
    int rb = wave & 1;
    int cb0 = (wave >> 1) * 2;
    const halfx8* bp0 = (const halfx8*)Wp + (size_t)cb0 * steps * 64 + lane;
    const halfx8* bp1 = bp0 + (size_t)steps * 64;
    const _Float16* arow = &As[(rb * 32 + (lane & 31)) * stride + ((lane >> 5) << 3)];
    f32x16 acc0 = {}, acc1 = {};
    for (int s = 0; s < steps; s++) {
        halfx8 a = *(const halfx8*)&arow[s * 16];
        acc0 = __builtin_amdgcn_mfma_f32_32x32x16_f16(a, bp0[s * 64], acc0, 0, 0, 0);
        acc1 = __builtin_amdgcn_mfma_f32_32x32x16_f16(a, bp1[s * 64], acc1, 0, 0, 0);
    }

    int colA = cb0 * 32 + (lane & 31);
    int colB = colA + 32;
    float bA = bias ? bias[colA] : 0.f;
    float bB = bias ? bias[colB] : 0.f;
#pragma unroll
    for (int r = 0; r < 16; r++) {
        int rl = (r & 3) + 8 * (r >> 2) + 4 * (lane >> 5);
        int grow = M0 + rb * 32 + rl;
        if (grow < M) {
            float sc = rowscale ? rowscale[grow] : 1.f;
            float v0 = (acc0[r] + bA) * sc;
            float v1 = (acc1[r] + bB) * sc;
            if (dorelu) { v0 = fmaxf(v0, 0.f); v1 = fmaxf(v1, 0.f); }
            out[(size_t)grow * 128 + colA] = (_Float16)v0;
            out[(size_t)grow * 128 + colB] = (_Float16)v1;
        }
    }
}

// Dual-output GEMM: U = A@WpU + bm1, V = A@WpV (A staged once).
__global__ __launch_bounds__(256) void gemm_uv_kernel(const _Float16* __restrict__ A,
                                                      const _Float16* __restrict__ WpU,
                                                      const _Float16* __restrict__ WpV,
                                                      const float* __restrict__ bm1,
                                                      _Float16* __restrict__ U,
                                                      _Float16* __restrict__ V,
                                                      int M) {
    const int K = 128, steps = 8;
    __shared__ _Float16 As[64 * 136];
    int tid = threadIdx.x;
    int M0 = blockIdx.x * 64;
    int stride = K + 8;
    for (int i = tid; i < 64 * 16; i += 256) {
        int r = i >> 4, c = i & 15;
        uint4 v = make_uint4(0, 0, 0, 0);
        int row = M0 + r;
        if (row < M) v = *(const uint4*)&A[(size_t)row * K + c * 8];
        *(uint4*)&As[r * stride + c * 8] = v;
    }
    __syncthreads();

    int wave = tid >> 6, lane = tid & 63;
    int rb = wave & 1;
    int cb0 = (wave >> 1) * 2;
    const halfx8* bu0 = (const halfx8*)WpU + (size_t)cb0 * steps * 64 + lane;
    const halfx8* bu1 = bu0 + (size_t)steps * 64;
    const halfx8* bv0 = (const halfx8*)WpV + (size_t)cb0 * steps * 64 + lane;
    const halfx8* bv1 = bv0 + (size_t)steps * 64;
    const _Float16* arow = &As[(rb * 32 + (lane & 31)) * stride + ((lane >> 5) << 3)];
    f32x16 au0 = {}, au1 = {}, av0 = {}, av1 = {};
    for (int s = 0; s < steps; s++) {
        halfx8 a = *(const halfx8*)&arow[s * 16];
        au0 = __builtin_amdgcn_mfma_f32_32x32x16_f16(a, bu0[s * 64], au0, 0, 0, 0);
        au1 = __builtin_amdgcn_mfma_f32_32x32x16_f16(a, bu1[s * 64], au1, 0, 0, 0);
        av0 = __builtin_amdgcn_mfma_f32_32x32x16_f16(a, bv0[s * 64], av0, 0, 0, 0);
        av1 = __builtin_amdgcn_mfma_f32_32x32x16_f16(a, bv1[s * 64], av1, 0, 0, 0);
    }

    int colA = cb0 * 32 + (lane & 31);
    int colB = colA + 32;
    float bA = bm1[colA], bB = bm1[colB];
#pragma unroll
    for (int r = 0; r < 16; r++) {
        int rl = (r & 3) + 8 * (r >> 2) + 4 * (lane >> 5);
        int grow = M0 + rb * 32 + rl;
        if (grow < M) {
            U[(size_t)grow * 128 + colA] = (_Float16)(au0[r] + bA);
            U[(size_t)grow * 128 + colB] = (_Float16)(au1[r] + bB);
            V[(size_t)grow * 128 + colA] = (_Float16)av0[r];
            V[(size_t)grow * 128 + colB] = (_Float16)av1[r];
        }
    }
}

// ---------------------------------------------------------------------------
// GCN aggregation: wave-per-node (12500 blocks — max gather parallelism).
// Round-6 proven. DO NOT fuse into the GEMM tile (round-7 regression).
// ---------------------------------------------------------------------------
__global__ __launch_bounds__(256) void aggregate_kernel(const _Float16* __restrict__ y,
                                                        const float* __restrict__ dinv,
                                                        const int* __restrict__ ptr,
                                                        const int2* __restrict__ ce_se,
                                                        const float* __restrict__ bias,
                                                        _Float16* __restrict__ out) {
    int node = blockIdx.x * 4 + (threadIdx.x >> 6);
    int lane = threadIdx.x & 63;
    int c = lane * 2;
    float di = dinv[node];
    half2v self = ((const half2v*)&y[(size_t)node * 128])[lane];
    float a0 = (float)self.x, a1 = (float)self.y;
    float b0 = 0.f, b1 = 0.f, c0 = 0.f, c1 = 0.f, d0 = 0.f, d1 = 0.f;
    int s0 = ptr[node], s1 = ptr[node + 1];
    int j = s0;
    for (; j + 7 < s1; j += 8) {
        int n0 = ce_se[j].x, n1 = ce_se[j + 1].x, n2 = ce_se[j + 2].x, n3 = ce_se[j + 3].x;
        int n4 = ce_se[j + 4].x, n5 = ce_se[j + 5].x, n6 = ce_se[j + 6].x, n7 = ce_se[j + 7].x;
        half2v v0 = ((const half2v*)&y[(size_t)n0 * 128])[lane];
        half2v v1 = ((const half2v*)&y[(size_t)n1 * 128])[lane];
        half2v v2 = ((const half2v*)&y[(size_t)n2 * 128])[lane];
        half2v v3 = ((const half2v*)&y[(size_t)n3 * 128])[lane];
        half2v v4 = ((const half2v*)&y[(size_t)n4 * 128])[lane];
        half2v v5 = ((const half2v*)&y[(size_t)n5 * 128])[lane];
        half2v v6 = ((const half2v*)&y[(size_t)n6 * 128])[lane];
        half2v v7 = ((const half2v*)&y[(size_t)n7 * 128])[lane];
        a0 += (float)v0.x + (float)v4.x; a1 += (float)v0.y + (float)v4.y;
        b0 += (float)v1.x + (float)v5.x; b1 += (float)v1.y + (float)v5.y;
        c0 += (float)v2.x + (float)v6.x; c1 += (float)v2.y + (float)v6.y;
        d0 += (float)v3.x + (float)v7.x; d1 += (float)v3.y + (float)v7.y;
    }
    for (; j < s1; j++) {
        int n = ce_se[j].x;
        half2v v = ((const half2v*)&y[(size_t)n * 128])[lane];
        a0 += (float)v.x; a1 += (float)v.y;
    }
    float2 bv = *(const float2*)&bias[c];
    float o0 = fmaxf(di * (a0 + b0 + c0 + d0) + bv.x, 0.f);
    float o1 = fmaxf(di * (a1 + b1 + c1 + d1) + bv.y, 0.f);
    half2v ov = {(_Float16)o0, (_Float16)o1};
    ((half2v*)&out[(size_t)node * 128])[lane] = ov;
}

// ---------------------------------------------------------------------------
// Edge MLP: 64 edges/block, 4 edges per 16-lane group (8 gathers in flight).
// ---------------------------------------------------------------------------
__global__ __launch_bounds__(256) void edge_mlp_kernel(const _Float16* __restrict__ Ub,
                                                       const _Float16* __restrict__ Vb,
                                                       const int2* __restrict__ ce_se,
                                                       const int* __restrict__ ce_dst,
                                                       const float* __restrict__ Wm2,
                                                       const float* __restrict__ bm2,
                                                       float* __restrict__ out) {
    __shared__ int ssrc[64], sdst[64], seid[64];
    int tid = threadIdx.x;
    int e0 = blockIdx.x * 64;
    if (tid < 64) {
        int2 se = ce_se[e0 + tid];
        ssrc[tid] = se.x;
        seid[tid] = se.y;
    } else if (tid < 128) {
        sdst[tid - 64] = ce_dst[e0 + tid - 64];
    }
    __syncthreads();
    int g = tid >> 4;
    int l = tid & 15;
    int ga = g, gb = g + 16, gc = g + 32, gd = g + 48;
    halfx8 u0 = *(const halfx8*)&Ub[(size_t)ssrc[ga] * 128 + l * 8];
    halfx8 v0 = *(const halfx8*)&Vb[(size_t)sdst[ga] * 128 + l * 8];
    halfx8 u1 = *(const halfx8*)&Ub[(size_t)ssrc[gb] * 128 + l * 8];
    halfx8 v1 = *(const halfx8*)&Vb[(size_t)sdst[gb] * 128 + l * 8];
    halfx8 u2 = *(const halfx8*)&Ub[(size_t)ssrc[gc] * 128 + l * 8];
    halfx8 v2 = *(const halfx8*)&Vb[(size_t)sdst[gc] * 128 + l * 8];
    halfx8 u3 = *(const halfx8*)&Ub[(size_t)ssrc[gd] * 128 + l * 8];
    halfx8 v3 = *(const halfx8*)&Vb[(size_t)sdst[gd] * 128 + l * 8];
    float4 w0 = *(const float4*)&Wm2[l * 8];
    float4 w1 = *(const float4*)&Wm2[l * 8 + 4];
    float wm[8] = {w0.x, w0.y, w0.z, w0.w, w1.x, w1.y, w1.z, w1.w};
    float p0 = 0.f, p1 = 0.f, p2 = 0.f, p3 = 0.f;
#pragma unroll
    for (int t = 0; t < 8; t++) {
        p0 = fmaf(fmaxf((float)u0[t] + (float)v0[t], 0.f), wm[t], p0);
        p1 = fmaf(fmaxf((float)u1[t] + (float)v1[t], 0.f), wm[t], p1);
        p2 = fmaf(fmaxf((float)u2[t] + (float)v2[t], 0.f), wm[t], p2);
        p3 = fmaf(fmaxf((float)u3[t] + (float)v3[t], 0.f), wm[t], p3);
    }
#pragma unroll
    for (int d = 1; d < 16; d <<= 1) {
        p0 += __shfl_xor(p0, d);
        p1 += __shfl_xor(p1, d);
        p2 += __shfl_xor(p2, d);
        p3 += __shfl_xor(p3, d);
    }
    if (l == 0) {
        float bb = bm2[0];
        out[seid[ga]] = p0 + bb;
        out[seid[gb]] = p1 + bb;
        out[seid[gc]] = p2 + bb;
        out[seid[gd]] = p3 + bb;
    }
}

// ---------------------------------------------------------------------------
extern "C" void kernel_launch(void* const* d_in, const int* in_sizes, int n_in,
                              void* d_out, int out_size, void* d_ws, size_t ws_size,
                              hipStream_t stream) {
    const float* x    = (const float*)d_in[0];
    const int* eidx   = (const int*)d_in[1];
    const float* W_in = (const float*)d_in[2];
    const float* b_in = (const float*)d_in[3];
    const float* W1   = (const float*)d_in[4];
    const float* b1   = (const float*)d_in[5];
    const float* W2   = (const float*)d_in[6];
    const float* b2   = (const float*)d_in[7];
    const float* Wm1  = (const float*)d_in[8];
    const float* bm1  = (const float*)d_in[9];
    const float* Wm2  = (const float*)d_in[10];
    const float* bm2  = (const float*)d_in[11];
    float* out = (float*)d_out;
    const int* src = eidx;
    const int* dst = eidx + N_EDGES;

    char* w = (char*)d_ws;
    size_t off = 0;
    auto alloc = [&](size_t bytes) -> char* {
        char* p = w + off;
        off = (off + bytes + 255) & ~(size_t)255;
        return p;
    };
    int* bhist    = (int*)alloc((size_t)NB * 4);
    int* boff     = (int*)alloc((size_t)(NB + 1) * 4);
    int* bcursor  = (int*)alloc((size_t)NB * 4);
    int* csr_ptr  = (int*)alloc((size_t)(N_NODES + 1) * 4);
    float* dinv   = (float*)alloc((size_t)N_NODES * 4);
    unsigned long long* binned = (unsigned long long*)alloc((size_t)N_EDGES * 8);
    int2* ce_se   = (int2*)alloc((size_t)N_EDGES * 8);
    int* ce_dst   = (int*)alloc((size_t)N_EDGES * 4);
    _Float16* Wp  = (_Float16*)alloc((size_t)77824 * 2);
    _Float16* y1  = (_Float16*)alloc((size_t)N_NODES * HID * 2);
    _Float16* y2  = (_Float16*)alloc((size_t)N_NODES * HID * 2);
    _Float16* hbuf = (_Float16*)alloc((size_t)N_NODES * HID * 2);
    _Float16* Ub  = (_Float16*)alloc((size_t)N_NODES * HID * 2);
    _Float16* Vb  = (_Float16*)alloc((size_t)N_NODES * HID * 2);

    const _Float16* WpIn  = Wp;              // K=96, steps 6
    const _Float16* Wp1   = Wp + 12288;      // K=128
    const _Float16* Wp2   = Wp + 28672;
    const _Float16* WpM1a = Wp + 45056;
    const _Float16* WpM1b = Wp + 61440;

    // CSR build (counting sort)
    hipMemsetAsync(bhist, 0, (size_t)NB * 4, stream);
    bucket_hist_kernel<<<196, 256, 0, stream>>>(dst, bhist);
    scan_buckets_kernel<<<1, 512, 0, stream>>>(bhist, boff, bcursor);
    bin_kernel<<<98, 512, 0, stream>>>(src, dst, bcursor, binned);
    bucket_sort_kernel<<<NB, 256, 0, stream>>>(binned, boff, ce_se, ce_dst, csr_ptr, dinv);
    pack_weights_kernel<<<(77824 + 255) / 256, 256, 0, stream>>>(W_in, W1, W2, Wm1, Wp);

    int gblocks = (N_NODES + 63) / 64;  // 782
    // y1 = (relu(x@W_in+b_in) @ W1) * dinv          (h0 LDS-only)
    fused_in_kernel<<<gblocks, 256, 0, stream>>>(x, WpIn, Wp1, b_in, dinv, y1, N_NODES);
    // h1 = relu(dinv*(y1_self + sum y1[src]) + b1)  -> hbuf
    aggregate_kernel<<<N_NODES / 4, 256, 0, stream>>>(y1, dinv, csr_ptr, ce_se, b1, hbuf);
    // y2 = (h1 @ W2) * dinv                         -> y2
    gemm_f16_kernel<<<gblocks, 256, 0, stream>>>(hbuf, Wp2, nullptr, dinv, y2,
                                                 N_NODES, HID, 8, 0);
    // h2 = relu(dinv*(y2_self + sum y2[src]) + b2)  -> hbuf
    aggregate_kernel<<<N_NODES / 4, 256, 0, stream>>>(y2, dinv, csr_ptr, ce_se, b2, hbuf);
    // U = h2@Wm1a+bm1, V = h2@Wm1b                  -> Ub, Vb
    gemm_uv_kernel<<<gblocks, 256, 0, stream>>>(hbuf, WpM1a, WpM1b, bm1, Ub, Vb, N_NODES);
    // logits (CSR order, scatter by original edge id)
    edge_mlp_kernel<<<N_EDGES / 64, 256, 0, stream>>>(Ub, Vb, ce_se, ce_dst, Wm2, bm2, out);
}

// Round 9
// 260.256 us; speedup vs baseline: 1.5550x; 1.0677x over previous
//
#include <hip/hip_runtime.h>

#define N_NODES 50000
#define N_EDGES 800000
#define D_IN 96
#define HID 128
#define NB 391              // buckets of 128 nodes
#define BCAP 3072

typedef __attribute__((ext_vector_type(8))) _Float16 halfx8;
typedef __attribute__((ext_vector_type(4))) _Float16 half4v;
typedef __attribute__((ext_vector_type(2))) _Float16 half2v;
typedef __attribute__((ext_vector_type(16))) float f32x16;

// ---------------------------------------------------------------------------
// CSR build via LDS-binned counting sort.
// ---------------------------------------------------------------------------
__global__ __launch_bounds__(256) void bucket_hist_kernel(const int* __restrict__ dst,
                                                          int* __restrict__ bhist) {
    __shared__ int lh[NB];
    int t = threadIdx.x;
    for (int i = t; i < NB; i += 256) lh[i] = 0;
    __syncthreads();
    int base = blockIdx.x * 4096;
#pragma unroll
    for (int i = 0; i < 16; i++) {
        int e = base + i * 256 + t;
        if (e < N_EDGES) atomicAdd(&lh[dst[e] >> 7], 1);
    }
    __syncthreads();
    for (int i = t; i < NB; i += 256) atomicAdd(&bhist[i], lh[i]);
}

__global__ __launch_bounds__(512) void scan_buckets_kernel(const int* __restrict__ bhist,
                                                           int* __restrict__ boff,
                                                           int* __restrict__ bcursor) {
    __shared__ int s[512];
    int t = threadIdx.x;
    int v = (t < NB) ? bhist[t] : 0;
    s[t] = v;
    __syncthreads();
    for (int off = 1; off < 512; off <<= 1) {
        int u = (t >= off) ? s[t - off] : 0;
        __syncthreads();
        s[t] += u;
        __syncthreads();
    }
    if (t < NB) {
        int ex = s[t] - v;
        boff[t] = ex;
        bcursor[t] = ex;
    }
    if (t == NB - 1) boff[NB] = s[t];
}

__global__ __launch_bounds__(512) void bin_kernel(const int* __restrict__ src,
                                                  const int* __restrict__ dst,
                                                  int* __restrict__ bcursor,
                                                  unsigned long long* __restrict__ binned) {
    __shared__ int lh[NB];
    __shared__ int gbs[NB];
    int t = threadIdx.x;
    for (int i = t; i < NB; i += 512) lh[i] = 0;
    __syncthreads();
    int base = blockIdx.x * 8192;
    unsigned long long pk[16];
    int bb[16], rk[16];
#pragma unroll
    for (int i = 0; i < 16; i++) {
        int e = base + i * 512 + t;
        bb[i] = -1;
        if (e < N_EDGES) {
            int s = src[e], d = dst[e];
            int b = d >> 7;
            bb[i] = b;
            pk[i] = ((unsigned long long)s << 27) |
                    ((unsigned long long)(d & 127) << 20) | (unsigned long long)e;
            rk[i] = atomicAdd(&lh[b], 1);
        }
    }
    __syncthreads();
    for (int i = t; i < NB; i += 512) gbs[i] = atomicAdd(&bcursor[i], lh[i]);
    __syncthreads();
#pragma unroll
    for (int i = 0; i < 16; i++) {
        if (bb[i] >= 0) binned[gbs[bb[i]] + rk[i]] = pk[i];
    }
}

__global__ __launch_bounds__(256) void bucket_sort_kernel(const unsigned long long* __restrict__ binned,
                                                          const int* __restrict__ boff,
                                                          int* __restrict__ ce_src,
                                                          int* __restrict__ ce_eid,
                                                          int* __restrict__ ce_dst,
                                                          int* __restrict__ csr_ptr,
                                                          float* __restrict__ dinv) {
    __shared__ unsigned long long ed[BCAP];
    __shared__ int2 sorted[BCAP];
    __shared__ int cntA[128], sc[128];
    int b = blockIdx.x;
    int t = threadIdx.x;
    int base = boff[b];
    int k = boff[b + 1] - base;
    if (k > BCAP) k = BCAP;
    if (t < 128) cntA[t] = 0;
    __syncthreads();
    int rk[12], li[12];
    int nmine = 0;
    for (int i = t; i < k; i += 256) {
        unsigned long long p = binned[base + i];
        ed[i] = p;
        int d = (int)((p >> 20) & 127);
        rk[nmine] = atomicAdd(&cntA[d], 1);
        li[nmine] = i;
        nmine++;
    }
    __syncthreads();
    if (t < 128) sc[t] = cntA[t];
    __syncthreads();
    for (int off = 1; off < 128; off <<= 1) {
        int u = 0;
        if (t < 128 && t >= off) u = sc[t - off];
        __syncthreads();
        if (t < 128) sc[t] += u;
        __syncthreads();
    }
    for (int m = 0; m < nmine; m++) {
        unsigned long long p = ed[li[m]];
        int d = (int)((p >> 20) & 127);
        int pos = sc[d] - cntA[d] + rk[m];
        int srcn = (int)(p >> 27);
        int eid = (int)(p & 0xFFFFF);
        sorted[pos] = make_int2(srcn | (d << 16), eid);
    }
    __syncthreads();
    for (int i = t; i < k; i += 256) {
        int2 se = sorted[i];
        ce_src[base + i] = se.x & 0xFFFF;
        ce_eid[base + i] = se.y;
        ce_dst[base + i] = (b << 7) + (se.x >> 16);
    }
    if (t < 128) {
        int node = (b << 7) + t;
        if (node < N_NODES) {
            csr_ptr[node] = base + sc[t] - cntA[t];
            dinv[node] = 1.0f / sqrtf((float)(cntA[t] + 1));
        }
    }
    if (b == NB - 1 && t == 0) csr_ptr[N_NODES] = boff[NB];
}

// ---------------------------------------------------------------------------
// Pack weights into MFMA B-fragment order (fp16).
// ---------------------------------------------------------------------------
__global__ __launch_bounds__(256) void pack_weights_kernel(const float* __restrict__ W_in,
                                                           const float* __restrict__ W1,
                                                           const float* __restrict__ W2,
                                                           const float* __restrict__ Wm1,
                                                           _Float16* __restrict__ packed) {
    int t = blockIdx.x * 256 + threadIdx.x;
    const float* Wsrc;
    int K, u;
    if (t < 12288)      { Wsrc = W_in;            K = 96;  u = t; }
    else if (t < 28672) { Wsrc = W1;              K = 128; u = t - 12288; }
    else if (t < 45056) { Wsrc = W2;              K = 128; u = t - 28672; }
    else if (t < 61440) { Wsrc = Wm1;             K = 128; u = t - 45056; }
    else                { Wsrc = Wm1 + 128 * 128; K = 128; u = t - 61440; }
    if (t >= 77824) return;
    int steps = K >> 4;
    int cb = u / (steps * 512);
    int rem = u - cb * steps * 512;
    int s = rem >> 9;
    int lane = (rem >> 3) & 63;
    int j = rem & 7;
    int k = s * 16 + ((lane >> 5) << 3) + j;
    int n = (cb << 5) + (lane & 31);
    packed[t] = (_Float16)Wsrc[k * 128 + n];
}

// ---------------------------------------------------------------------------
// Fused input: y1 = (relu(x@W_in + b_in) @ W1) * dinv[row]. h0 LDS-only.
// M=32 tile, 4 waves = 4 col-tiles of 32.
// ---------------------------------------------------------------------------
__global__ __launch_bounds__(256) void fused_in_kernel(const float* __restrict__ x,
                                                       const _Float16* __restrict__ WpIn,
                                                       const _Float16* __restrict__ Wp1,
                                                       const float* __restrict__ b_in,
                                                       const float* __restrict__ dinv,
                                                       _Float16* __restrict__ y1, int M) {
    __shared__ _Float16 As[32 * 104];
    __shared__ _Float16 Hs[32 * 136];
    int tid = threadIdx.x;
    int M0 = blockIdx.x * 32;
    // stage x (fp32 -> fp16): 32 rows x 24 float4 chunks = 768
    for (int i = tid; i < 32 * 24; i += 256) {
        int r = i / 24, c = i - r * 24;
        float4 v = make_float4(0.f, 0.f, 0.f, 0.f);
        int row = M0 + r;
        if (row < M) v = *(const float4*)&x[(size_t)row * 96 + c * 4];
        half2v a = {(_Float16)v.x, (_Float16)v.y};
        half2v b = {(_Float16)v.z, (_Float16)v.w};
        *(half2v*)&As[r * 104 + c * 4] = a;
        *(half2v*)&As[r * 104 + c * 4 + 2] = b;
    }
    __syncthreads();

    int wave = tid >> 6, lane = tid & 63;
    int col = wave * 32 + (lane & 31);
    // phase 1: h0 = relu(x@W_in + b_in) -> Hs
    {
        const halfx8* bp = (const halfx8*)WpIn + (size_t)wave * 6 * 64 + lane;
        const _Float16* arow = &As[(lane & 31) * 104 + ((lane >> 5) << 3)];
        f32x16 acc = {};
#pragma unroll
        for (int s = 0; s < 6; s++) {
            halfx8 a = *(const halfx8*)&arow[s * 16];
            acc = __builtin_amdgcn_mfma_f32_32x32x16_f16(a, bp[s * 64], acc, 0, 0, 0);
        }
        float bA = b_in[col];
#pragma unroll
        for (int r = 0; r < 16; r++) {
            int rl = (r & 3) + 8 * (r >> 2) + 4 * (lane >> 5);
            Hs[rl * 136 + col] = (_Float16)fmaxf(acc[r] + bA, 0.f);
        }
    }
    __syncthreads();
    // phase 2: y1 = (h0 @ W1) * dinv
    {
        const halfx8* bp = (const halfx8*)Wp1 + (size_t)wave * 8 * 64 + lane;
        const _Float16* arow = &Hs[(lane & 31) * 136 + ((lane >> 5) << 3)];
        f32x16 acc = {};
#pragma unroll
        for (int s = 0; s < 8; s++) {
            halfx8 a = *(const halfx8*)&arow[s * 16];
            acc = __builtin_amdgcn_mfma_f32_32x32x16_f16(a, bp[s * 64], acc, 0, 0, 0);
        }
#pragma unroll
        for (int r = 0; r < 16; r++) {
            int rl = (r & 3) + 8 * (r >> 2) + 4 * (lane >> 5);
            int grow = M0 + rl;
            if (grow < M) {
                y1[(size_t)grow * 128 + col] = (_Float16)(acc[r] * dinv[grow]);
            }
        }
    }
}

// ---------------------------------------------------------------------------
// fp16 MFMA node GEMM, M=32 tile, wave = col-tile.
// ---------------------------------------------------------------------------
__global__ __launch_bounds__(256) void gemm_f16_kernel(const _Float16* __restrict__ A,
                                                       const _Float16* __restrict__ Wp,
                                                       const float* __restrict__ bias,
                                                       const float* __restrict__ rowscale,
                                                       _Float16* __restrict__ out,
                                                       int M, int K, int steps, int dorelu) {
    __shared__ _Float16 As[32 * 136];
    int tid = threadIdx.x;
    int M0 = blockIdx.x * 32;
    int stride = K + 8;
    int CH = K >> 3;
    int tot = 32 * CH;
    for (int i = tid; i < tot; i += 256) {
        int r = i / CH, c = i - r * CH;
        uint4 v = make_uint4(0, 0, 0, 0);
        int row = M0 + r;
        if (row < M) v = *(const uint4*)&A[(size_t)row * K + c * 8];
        *(uint4*)&As[r * stride + c * 8] = v;
    }
    __syncthreads();

    int wave = tid >> 6, lane = tid & 63;
    const halfx8* bp = (const halfx8*)Wp + (size_t)wave * steps * 64 + lane;
    const _Float16* arow = &As[(lane & 31) * stride + ((lane >> 5) << 3)];
    f32x16 acc = {};
    for (int s = 0; s < steps; s++) {
        halfx8 a = *(const halfx8*)&arow[s * 16];
        acc = __builtin_amdgcn_mfma_f32_32x32x16_f16(a, bp[s * 64], acc, 0, 0, 0);
    }
    int col = wave * 32 + (lane & 31);
    float bA = bias ? bias[col] : 0.f;
#pragma unroll
    for (int r = 0; r < 16; r++) {
        int rl = (r & 3) + 8 * (r >> 2) + 4 * (lane >> 5);
        int grow = M0 + rl;
        if (grow < M) {
            float sc = rowscale ? rowscale[grow] : 1.f;
            float v0 = (acc[r] + bA) * sc;
            if (dorelu) v0 = fmaxf(v0, 0.f);
            out[(size_t)grow * 128 + col] = (_Float16)v0;
        }
    }
}

// Dual-output GEMM: U = A@WpU + bm1, V = A@WpV (A staged once). M=32 tile.
__global__ __launch_bounds__(256) void gemm_uv_kernel(const _Float16* __restrict__ A,
                                                      const _Float16* __restrict__ WpU,
                                                      const _Float16* __restrict__ WpV,
                                                      const float* __restrict__ bm1,
                                                      _Float16* __restrict__ U,
                                                      _Float16* __restrict__ V,
                                                      int M) {
    const int K = 128, steps = 8;
    __shared__ _Float16 As[32 * 136];
    int tid = threadIdx.x;
    int M0 = blockIdx.x * 32;
    int stride = K + 8;
    for (int i = tid; i < 32 * 16; i += 256) {
        int r = i >> 4, c = i & 15;
        uint4 v = make_uint4(0, 0, 0, 0);
        int row = M0 + r;
        if (row < M) v = *(const uint4*)&A[(size_t)row * K + c * 8];
        *(uint4*)&As[r * stride + c * 8] = v;
    }
    __syncthreads();

    int wave = tid >> 6, lane = tid & 63;
    const halfx8* bu = (const halfx8*)WpU + (size_t)wave * steps * 64 + lane;
    const halfx8* bv = (const halfx8*)WpV + (size_t)wave * steps * 64 + lane;
    const _Float16* arow = &As[(lane & 31) * stride + ((lane >> 5) << 3)];
    f32x16 au = {}, av = {};
#pragma unroll
    for (int s = 0; s < steps; s++) {
        halfx8 a = *(const halfx8*)&arow[s * 16];
        au = __builtin_amdgcn_mfma_f32_32x32x16_f16(a, bu[s * 64], au, 0, 0, 0);
        av = __builtin_amdgcn_mfma_f32_32x32x16_f16(a, bv[s * 64], av, 0, 0, 0);
    }
    int col = wave * 32 + (lane & 31);
    float bA = bm1[col];
#pragma unroll
    for (int r = 0; r < 16; r++) {
        int rl = (r & 3) + 8 * (r >> 2) + 4 * (lane >> 5);
        int grow = M0 + rl;
        if (grow < M) {
            U[(size_t)grow * 128 + col] = (_Float16)(au[r] + bA);
            V[(size_t)grow * 128 + col] = (_Float16)av[r];
        }
    }
}

// ---------------------------------------------------------------------------
// GCN aggregation: half-wave per node (32 lanes x 4 cols, 8 B/lane).
// Two independent gather streams share one instruction stream -> 16 row
// loads in flight per wave. 6250 blocks. DO NOT fuse into GEMM (R7 lesson).
// ---------------------------------------------------------------------------
__global__ __launch_bounds__(256) void aggregate_kernel(const _Float16* __restrict__ y,
                                                        const float* __restrict__ dinv,
                                                        const int* __restrict__ ptr,
                                                        const int* __restrict__ ce_src,
                                                        const float* __restrict__ bias,
                                                        _Float16* __restrict__ out) {
    int node = blockIdx.x * 8 + (threadIdx.x >> 5);
    int l = threadIdx.x & 31;
    float di = dinv[node];
    half4v self = ((const half4v*)&y[(size_t)node * 128])[l];
    float a0 = (float)self[0], a1 = (float)self[1], a2 = (float)self[2], a3 = (float)self[3];
    float b0 = 0.f, b1 = 0.f, b2 = 0.f, b3 = 0.f;
    int s0 = ptr[node], s1 = ptr[node + 1];
    int j = s0;
    for (; j + 7 < s1; j += 8) {
        int n0 = ce_src[j], n1 = ce_src[j + 1], n2 = ce_src[j + 2], n3 = ce_src[j + 3];
        int n4 = ce_src[j + 4], n5 = ce_src[j + 5], n6 = ce_src[j + 6], n7 = ce_src[j + 7];
        half4v v0 = ((const half4v*)&y[(size_t)n0 * 128])[l];
        half4v v1 = ((const half4v*)&y[(size_t)n1 * 128])[l];
        half4v v2 = ((const half4v*)&y[(size_t)n2 * 128])[l];
        half4v v3 = ((const half4v*)&y[(size_t)n3 * 128])[l];
        half4v v4 = ((const half4v*)&y[(size_t)n4 * 128])[l];
        half4v v5 = ((const half4v*)&y[(size_t)n5 * 128])[l];
        half4v v6 = ((const half4v*)&y[(size_t)n6 * 128])[l];
        half4v v7 = ((const half4v*)&y[(size_t)n7 * 128])[l];
        a0 += (float)v0[0] + (float)v2[0] + (float)v4[0] + (float)v6[0];
        a1 += (float)v0[1] + (float)v2[1] + (float)v4[1] + (float)v6[1];
        a2 += (float)v0[2] + (float)v2[2] + (float)v4[2] + (float)v6[2];
        a3 += (float)v0[3] + (float)v2[3] + (float)v4[3] + (float)v6[3];
        b0 += (float)v1[0] + (float)v3[0] + (float)v5[0] + (float)v7[0];
        b1 += (float)v1[1] + (float)v3[1] + (float)v5[1] + (float)v7[1];
        b2 += (float)v1[2] + (float)v3[2] + (float)v5[2] + (float)v7[2];
        b3 += (float)v1[3] + (float)v3[3] + (float)v5[3] + (float)v7[3];
    }
    for (; j < s1; j++) {
        int n = ce_src[j];
        half4v v = ((const half4v*)&y[(size_t)n * 128])[l];
        a0 += (float)v[0]; a1 += (float)v[1]; a2 += (float)v[2]; a3 += (float)v[3];
    }
    float4 bv = *(const float4*)&bias[l * 4];
    half4v ov;
    ov[0] = (_Float16)fmaxf(di * (a0 + b0) + bv.x, 0.f);
    ov[1] = (_Float16)fmaxf(di * (a1 + b1) + bv.y, 0.f);
    ov[2] = (_Float16)fmaxf(di * (a2 + b2) + bv.z, 0.f);
    ov[3] = (_Float16)fmaxf(di * (a3 + b3) + bv.w, 0.f);
    ((half4v*)&out[(size_t)node * 128])[l] = ov;
}

// ---------------------------------------------------------------------------
// Edge MLP: 64 edges/block, 4 edges per 16-lane group (8 gathers in flight).
// ---------------------------------------------------------------------------
__global__ __launch_bounds__(256) void edge_mlp_kernel(const _Float16* __restrict__ Ub,
                                                       const _Float16* __restrict__ Vb,
                                                       const int* __restrict__ ce_src,
                                                       const int* __restrict__ ce_eid,
                                                       const int* __restrict__ ce_dst,
                                                       const float* __restrict__ Wm2,
                                                       const float* __restrict__ bm2,
                                                       float* __restrict__ out) {
    __shared__ int ssrc[64], sdst[64], seid[64];
    int tid = threadIdx.x;
    int e0 = blockIdx.x * 64;
    if (tid < 64) {
        ssrc[tid] = ce_src[e0 + tid];
        seid[tid] = ce_eid[e0 + tid];
    } else if (tid < 128) {
        sdst[tid - 64] = ce_dst[e0 + tid - 64];
    }
    __syncthreads();
    int g = tid >> 4;
    int l = tid & 15;
    int ga = g, gb = g + 16, gc = g + 32, gd = g + 48;
    halfx8 u0 = *(const halfx8*)&Ub[(size_t)ssrc[ga] * 128 + l * 8];
    halfx8 v0 = *(const halfx8*)&Vb[(size_t)sdst[ga] * 128 + l * 8];
    halfx8 u1 = *(const halfx8*)&Ub[(size_t)ssrc[gb] * 128 + l * 8];
    halfx8 v1 = *(const halfx8*)&Vb[(size_t)sdst[gb] * 128 + l * 8];
    halfx8 u2 = *(const halfx8*)&Ub[(size_t)ssrc[gc] * 128 + l * 8];
    halfx8 v2 = *(const halfx8*)&Vb[(size_t)sdst[gc] * 128 + l * 8];
    halfx8 u3 = *(const halfx8*)&Ub[(size_t)ssrc[gd] * 128 + l * 8];
    halfx8 v3 = *(const halfx8*)&Vb[(size_t)sdst[gd] * 128 + l * 8];
    float4 w0 = *(const float4*)&Wm2[l * 8];
    float4 w1 = *(const float4*)&Wm2[l * 8 + 4];
    float wm[8] = {w0.x, w0.y, w0.z, w0.w, w1.x, w1.y, w1.z, w1.w};
    float p0 = 0.f, p1 = 0.f, p2 = 0.f, p3 = 0.f;
#pragma unroll
    for (int t = 0; t < 8; t++) {
        p0 = fmaf(fmaxf((float)u0[t] + (float)v0[t], 0.f), wm[t], p0);
        p1 = fmaf(fmaxf((float)u1[t] + (float)v1[t], 0.f), wm[t], p1);
        p2 = fmaf(fmaxf((float)u2[t] + (float)v2[t], 0.f), wm[t], p2);
        p3 = fmaf(fmaxf((float)u3[t] + (float)v3[t], 0.f), wm[t], p3);
    }
#pragma unroll
    for (int d = 1; d < 16; d <<= 1) {
        p0 += __shfl_xor(p0, d);
        p1 += __shfl_xor(p1, d);
        p2 += __shfl_xor(p2, d);
        p3 += __shfl_xor(p3, d);
    }
    if (l == 0) {
        float bb = bm2[0];
        out[seid[ga]] = p0 + bb;
        out[seid[gb]] = p1 + bb;
        out[seid[gc]] = p2 + bb;
        out[seid[gd]] = p3 + bb;
    }
}

// ---------------------------------------------------------------------------
extern "C" void kernel_launch(void* const* d_in, const int* in_sizes, int n_in,
                              void* d_out, int out_size, void* d_ws, size_t ws_size,
                              hipStream_t stream) {
    const float* x    = (const float*)d_in[0];
    const int* eidx   = (const int*)d_in[1];
    const float* W_in = (const float*)d_in[2];
    const float* b_in = (const float*)d_in[3];
    const float* W1   = (const float*)d_in[4];
    const float* b1   = (const float*)d_in[5];
    const float* W2   = (const float*)d_in[6];
    const float* b2   = (const float*)d_in[7];
    const float* Wm1  = (const float*)d_in[8];
    const float* bm1  = (const float*)d_in[9];
    const float* Wm2  = (const float*)d_in[10];
    const float* bm2  = (const float*)d_in[11];
    float* out = (float*)d_out;
    const int* src = eidx;
    const int* dst = eidx + N_EDGES;

    char* w = (char*)d_ws;
    size_t off = 0;
    auto alloc = [&](size_t bytes) -> char* {
        char* p = w + off;
        off = (off + bytes + 255) & ~(size_t)255;
        return p;
    };
    int* bhist    = (int*)alloc((size_t)NB * 4);
    int* boff     = (int*)alloc((size_t)(NB + 1) * 4);
    int* bcursor  = (int*)alloc((size_t)NB * 4);
    int* csr_ptr  = (int*)alloc((size_t)(N_NODES + 1) * 4);
    float* dinv   = (float*)alloc((size_t)N_NODES * 4);
    unsigned long long* binned = (unsigned long long*)alloc((size_t)N_EDGES * 8);
    int* ce_src   = (int*)alloc((size_t)N_EDGES * 4);
    int* ce_eid   = (int*)alloc((size_t)N_EDGES * 4);
    int* ce_dst   = (int*)alloc((size_t)N_EDGES * 4);
    _Float16* Wp  = (_Float16*)alloc((size_t)77824 * 2);
    _Float16* y1  = (_Float16*)alloc((size_t)N_NODES * HID * 2);
    _Float16* y2  = (_Float16*)alloc((size_t)N_NODES * HID * 2);
    _Float16* hbuf = (_Float16*)alloc((size_t)N_NODES * HID * 2);
    _Float16* Ub  = (_Float16*)alloc((size_t)N_NODES * HID * 2);
    _Float16* Vb  = (_Float16*)alloc((size_t)N_NODES * HID * 2);

    const _Float16* WpIn  = Wp;              // K=96, steps 6
    const _Float16* Wp1   = Wp + 12288;      // K=128
    const _Float16* Wp2   = Wp + 28672;
    const _Float16* WpM1a = Wp + 45056;
    const _Float16* WpM1b = Wp + 61440;

    // CSR build (counting sort)
    hipMemsetAsync(bhist, 0, (size_t)NB * 4, stream);
    bucket_hist_kernel<<<196, 256, 0, stream>>>(dst, bhist);
    scan_buckets_kernel<<<1, 512, 0, stream>>>(bhist, boff, bcursor);
    bin_kernel<<<98, 512, 0, stream>>>(src, dst, bcursor, binned);
    bucket_sort_kernel<<<NB, 256, 0, stream>>>(binned, boff, ce_src, ce_eid, ce_dst,
                                               csr_ptr, dinv);
    pack_weights_kernel<<<(77824 + 255) / 256, 256, 0, stream>>>(W_in, W1, W2, Wm1, Wp);

    int gblocks = (N_NODES + 31) / 32;  // 1563
    // y1 = (relu(x@W_in+b_in) @ W1) * dinv          (h0 LDS-only)
    fused_in_kernel<<<gblocks, 256, 0, stream>>>(x, WpIn, Wp1, b_in, dinv, y1, N_NODES);
    // h1 = relu(dinv*(y1_self + sum y1[src]) + b1)  -> hbuf
    aggregate_kernel<<<N_NODES / 8, 256, 0, stream>>>(y1, dinv, csr_ptr, ce_src, b1, hbuf);
    // y2 = (h1 @ W2) * dinv                         -> y2
    gemm_f16_kernel<<<gblocks, 256, 0, stream>>>(hbuf, Wp2, nullptr, dinv, y2,
                                                 N_NODES, HID, 8, 0);
    // h2 = relu(dinv*(y2_self + sum y2[src]) + b2)  -> hbuf
    aggregate_kernel<<<N_NODES / 8, 256, 0, stream>>>(y2, dinv, csr_ptr, ce_src, b2, hbuf);
    // U = h2@Wm1a+bm1, V = h2@Wm1b                  -> Ub, Vb
    gemm_uv_kernel<<<gblocks, 256, 0, stream>>>(hbuf, WpM1a, WpM1b, bm1, Ub, Vb, N_NODES);
    // logits (CSR order, scatter by original edge id)
    edge_mlp_kernel<<<N_EDGES / 64, 256, 0, stream>>>(Ub, Vb, ce_src, ce_eid, ce_dst,
                                                      Wm2, bm2, out);
}

// Round 10
// 256.457 us; speedup vs baseline: 1.5781x; 1.0148x over previous
//
#include <hip/hip_runtime.h>

#define N_NODES 50000
#define N_EDGES 800000
#define D_IN 96
#define HID 128
#define NB 391              // buckets of 128 nodes
#define BCAP 3072

typedef __attribute__((ext_vector_type(8))) _Float16 halfx8;
typedef __attribute__((ext_vector_type(4))) _Float16 half4v;
typedef __attribute__((ext_vector_type(2))) _Float16 half2v;
typedef __attribute__((ext_vector_type(16))) float f32x16;

__device__ inline float dot2acc(half2v a, half2v b, float c) {
#if __has_builtin(__builtin_amdgcn_fdot2)
    return __builtin_amdgcn_fdot2(a, b, c, false);
#else
    return c + (float)a[0] * (float)b[0] + (float)a[1] * (float)b[1];
#endif
}

__device__ inline halfx8 relu8(halfx8 s) {
#if __has_builtin(__builtin_elementwise_max)
    return __builtin_elementwise_max(s, (halfx8)0);
#else
    halfx8 r;
#pragma unroll
    for (int i = 0; i < 8; i++) r[i] = s[i] > (_Float16)0 ? s[i] : (_Float16)0;
    return r;
#endif
}

// ---------------------------------------------------------------------------
// Merged: bucket histogram (blocks 0..195) + weight pack (blocks 196..500).
// Pack layout: W_in@0(12288), W1@12288, W2@28672, Wm1a@45056, Wm1b@61440,
// Wm2h@77824 (128).
// ---------------------------------------------------------------------------
__global__ __launch_bounds__(256) void hist_pack_kernel(const int* __restrict__ dst,
                                                        int* __restrict__ bhist,
                                                        const float* __restrict__ W_in,
                                                        const float* __restrict__ W1,
                                                        const float* __restrict__ W2,
                                                        const float* __restrict__ Wm1,
                                                        const float* __restrict__ Wm2,
                                                        _Float16* __restrict__ packed) {
    __shared__ int lh[NB];
    int t = threadIdx.x;
    if (blockIdx.x < 196) {
        for (int i = t; i < NB; i += 256) lh[i] = 0;
        __syncthreads();
        int base = blockIdx.x * 4096;
#pragma unroll
        for (int i = 0; i < 16; i++) {
            int e = base + i * 256 + t;
            if (e < N_EDGES) atomicAdd(&lh[dst[e] >> 7], 1);
        }
        __syncthreads();
        for (int i = t; i < NB; i += 256) atomicAdd(&bhist[i], lh[i]);
        return;
    }
    int g = (blockIdx.x - 196) * 256 + t;
    if (g >= 77952) return;
    if (g >= 77824) { packed[g] = (_Float16)Wm2[g - 77824]; return; }
    const float* Wsrc;
    int K, u;
    if (g < 12288)      { Wsrc = W_in;            K = 96;  u = g; }
    else if (g < 28672) { Wsrc = W1;              K = 128; u = g - 12288; }
    else if (g < 45056) { Wsrc = W2;              K = 128; u = g - 28672; }
    else if (g < 61440) { Wsrc = Wm1;             K = 128; u = g - 45056; }
    else                { Wsrc = Wm1 + 128 * 128; K = 128; u = g - 61440; }
    int steps = K >> 4;
    int cb = u / (steps * 512);
    int rem = u - cb * steps * 512;
    int s = rem >> 9;
    int lane = (rem >> 3) & 63;
    int j = rem & 7;
    int k = s * 16 + ((lane >> 5) << 3) + j;
    int n = (cb << 5) + (lane & 31);
    packed[g] = (_Float16)Wsrc[k * 128 + n];
}

__global__ __launch_bounds__(512) void scan_buckets_kernel(const int* __restrict__ bhist,
                                                           int* __restrict__ boff,
                                                           int* __restrict__ bcursor) {
    __shared__ int s[512];
    int t = threadIdx.x;
    int v = (t < NB) ? bhist[t] : 0;
    s[t] = v;
    __syncthreads();
    for (int off = 1; off < 512; off <<= 1) {
        int u = (t >= off) ? s[t - off] : 0;
        __syncthreads();
        s[t] += u;
        __syncthreads();
    }
    if (t < NB) {
        int ex = s[t] - v;
        boff[t] = ex;
        bcursor[t] = ex;
    }
    if (t == NB - 1) boff[NB] = s[t];
}

__global__ __launch_bounds__(512) void bin_kernel(const int* __restrict__ src,
                                                  const int* __restrict__ dst,
                                                  int* __restrict__ bcursor,
                                                  unsigned long long* __restrict__ binned) {
    __shared__ int lh[NB];
    __shared__ int gbs[NB];
    int t = threadIdx.x;
    for (int i = t; i < NB; i += 512) lh[i] = 0;
    __syncthreads();
    int base = blockIdx.x * 8192;
    unsigned long long pk[16];
    int bb[16], rk[16];
#pragma unroll
    for (int i = 0; i < 16; i++) {
        int e = base + i * 512 + t;
        bb[i] = -1;
        if (e < N_EDGES) {
            int s = src[e], d = dst[e];
            int b = d >> 7;
            bb[i] = b;
            pk[i] = ((unsigned long long)s << 27) |
                    ((unsigned long long)(d & 127) << 20) | (unsigned long long)e;
            rk[i] = atomicAdd(&lh[b], 1);
        }
    }
    __syncthreads();
    for (int i = t; i < NB; i += 512) gbs[i] = atomicAdd(&bcursor[i], lh[i]);
    __syncthreads();
#pragma unroll
    for (int i = 0; i < 16; i++) {
        if (bb[i] >= 0) binned[gbs[bb[i]] + rk[i]] = pk[i];
    }
}

__global__ __launch_bounds__(256) void bucket_sort_kernel(const unsigned long long* __restrict__ binned,
                                                          const int* __restrict__ boff,
                                                          int* __restrict__ ce_src,
                                                          int* __restrict__ ce_eid,
                                                          int* __restrict__ ce_dst,
                                                          int* __restrict__ csr_ptr,
                                                          float* __restrict__ dinv) {
    __shared__ unsigned long long ed[BCAP];
    __shared__ int2 sorted[BCAP];
    __shared__ int cntA[128], sc[128];
    int b = blockIdx.x;
    int t = threadIdx.x;
    int base = boff[b];
    int k = boff[b + 1] - base;
    if (k > BCAP) k = BCAP;
    if (t < 128) cntA[t] = 0;
    __syncthreads();
    int rk[12], li[12];
    int nmine = 0;
    for (int i = t; i < k; i += 256) {
        unsigned long long p = binned[base + i];
        ed[i] = p;
        int d = (int)((p >> 20) & 127);
        rk[nmine] = atomicAdd(&cntA[d], 1);
        li[nmine] = i;
        nmine++;
    }
    __syncthreads();
    if (t < 128) sc[t] = cntA[t];
    __syncthreads();
    for (int off = 1; off < 128; off <<= 1) {
        int u = 0;
        if (t < 128 && t >= off) u = sc[t - off];
        __syncthreads();
        if (t < 128) sc[t] += u;
        __syncthreads();
    }
    for (int m = 0; m < nmine; m++) {
        unsigned long long p = ed[li[m]];
        int d = (int)((p >> 20) & 127);
        int pos = sc[d] - cntA[d] + rk[m];
        int srcn = (int)(p >> 27);
        int eid = (int)(p & 0xFFFFF);
        sorted[pos] = make_int2(srcn | (d << 16), eid);
    }
    __syncthreads();
    for (int i = t; i < k; i += 256) {
        int2 se = sorted[i];
        ce_src[base + i] = se.x & 0xFFFF;
        ce_eid[base + i] = se.y;
        ce_dst[base + i] = (b << 7) + (se.x >> 16);
    }
    if (t < 128) {
        int node = (b << 7) + t;
        if (node < N_NODES) {
            csr_ptr[node] = base + sc[t] - cntA[t];
            dinv[node] = 1.0f / sqrtf((float)(cntA[t] + 1));
        }
    }
    if (b == NB - 1 && t == 0) csr_ptr[N_NODES] = boff[NB];
}

// ---------------------------------------------------------------------------
// Fused input: y1 = (relu(x@W_in + b_in) @ W1) * dinv[row]. h0 LDS-only.
// ---------------------------------------------------------------------------
__global__ __launch_bounds__(256) void fused_in_kernel(const float* __restrict__ x,
                                                       const _Float16* __restrict__ WpIn,
                                                       const _Float16* __restrict__ Wp1,
                                                       const float* __restrict__ b_in,
                                                       const float* __restrict__ dinv,
                                                       _Float16* __restrict__ y1, int M) {
    __shared__ _Float16 As[32 * 104];
    __shared__ _Float16 Hs[32 * 136];
    int tid = threadIdx.x;
    int M0 = blockIdx.x * 32;
    for (int i = tid; i < 32 * 24; i += 256) {
        int r = i / 24, c = i - r * 24;
        float4 v = make_float4(0.f, 0.f, 0.f, 0.f);
        int row = M0 + r;
        if (row < M) v = *(const float4*)&x[(size_t)row * 96 + c * 4];
        half2v a = {(_Float16)v.x, (_Float16)v.y};
        half2v b = {(_Float16)v.z, (_Float16)v.w};
        *(half2v*)&As[r * 104 + c * 4] = a;
        *(half2v*)&As[r * 104 + c * 4 + 2] = b;
    }
    __syncthreads();

    int wave = tid >> 6, lane = tid & 63;
    int col = wave * 32 + (lane & 31);
    {
        const halfx8* bp = (const halfx8*)WpIn + (size_t)wave * 6 * 64 + lane;
        const _Float16* arow = &As[(lane & 31) * 104 + ((lane >> 5) << 3)];
        f32x16 acc = {};
#pragma unroll
        for (int s = 0; s < 6; s++) {
            halfx8 a = *(const halfx8*)&arow[s * 16];
            acc = __builtin_amdgcn_mfma_f32_32x32x16_f16(a, bp[s * 64], acc, 0, 0, 0);
        }
        float bA = b_in[col];
#pragma unroll
        for (int r = 0; r < 16; r++) {
            int rl = (r & 3) + 8 * (r >> 2) + 4 * (lane >> 5);
            Hs[rl * 136 + col] = (_Float16)fmaxf(acc[r] + bA, 0.f);
        }
    }
    __syncthreads();
    {
        const halfx8* bp = (const halfx8*)Wp1 + (size_t)wave * 8 * 64 + lane;
        const _Float16* arow = &Hs[(lane & 31) * 136 + ((lane >> 5) << 3)];
        f32x16 acc = {};
#pragma unroll
        for (int s = 0; s < 8; s++) {
            halfx8 a = *(const halfx8*)&arow[s * 16];
            acc = __builtin_amdgcn_mfma_f32_32x32x16_f16(a, bp[s * 64], acc, 0, 0, 0);
        }
#pragma unroll
        for (int r = 0; r < 16; r++) {
            int rl = (r & 3) + 8 * (r >> 2) + 4 * (lane >> 5);
            int grow = M0 + rl;
            if (grow < M) {
                y1[(size_t)grow * 128 + col] = (_Float16)(acc[r] * dinv[grow]);
            }
        }
    }
}

// ---------------------------------------------------------------------------
// fp16 MFMA node GEMM, M=32 tile, wave = col-tile.
// ---------------------------------------------------------------------------
__global__ __launch_bounds__(256) void gemm_f16_kernel(const _Float16* __restrict__ A,
                                                       const _Float16* __restrict__ Wp,
                                                       const float* __restrict__ bias,
                                                       const float* __restrict__ rowscale,
                                                       _Float16* __restrict__ out,
                                                       int M, int K, int steps, int dorelu) {
    __shared__ _Float16 As[32 * 136];
    int tid = threadIdx.x;
    int M0 = blockIdx.x * 32;
    int stride = K + 8;
    int CH = K >> 3;
    int tot = 32 * CH;
    for (int i = tid; i < tot; i += 256) {
        int r = i / CH, c = i - r * CH;
        uint4 v = make_uint4(0, 0, 0, 0);
        int row = M0 + r;
        if (row < M) v = *(const uint4*)&A[(size_t)row * K + c * 8];
        *(uint4*)&As[r * stride + c * 8] = v;
    }
    __syncthreads();

    int wave = tid >> 6, lane = tid & 63;
    const halfx8* bp = (const halfx8*)Wp + (size_t)wave * steps * 64 + lane;
    const _Float16* arow = &As[(lane & 31) * stride + ((lane >> 5) << 3)];
    f32x16 acc = {};
    for (int s = 0; s < steps; s++) {
        halfx8 a = *(const halfx8*)&arow[s * 16];
        acc = __builtin_amdgcn_mfma_f32_32x32x16_f16(a, bp[s * 64], acc, 0, 0, 0);
    }
    int col = wave * 32 + (lane & 31);
    float bA = bias ? bias[col] : 0.f;
#pragma unroll
    for (int r = 0; r < 16; r++) {
        int rl = (r & 3) + 8 * (r >> 2) + 4 * (lane >> 5);
        int grow = M0 + rl;
        if (grow < M) {
            float sc = rowscale ? rowscale[grow] : 1.f;
            float v0 = (acc[r] + bA) * sc;
            if (dorelu) v0 = fmaxf(v0, 0.f);
            out[(size_t)grow * 128 + col] = (_Float16)v0;
        }
    }
}

// Dual-output GEMM: U = A@WpU + bm1, V = A@WpV (A staged once). M=32 tile.
__global__ __launch_bounds__(256) void gemm_uv_kernel(const _Float16* __restrict__ A,
                                                      const _Float16* __restrict__ WpU,
                                                      const _Float16* __restrict__ WpV,
                                                      const float* __restrict__ bm1,
                                                      _Float16* __restrict__ U,
                                                      _Float16* __restrict__ V,
                                                      int M) {
    const int K = 128, steps = 8;
    __shared__ _Float16 As[32 * 136];
    int tid = threadIdx.x;
    int M0 = blockIdx.x * 32;
    int stride = K + 8;
    for (int i = tid; i < 32 * 16; i += 256) {
        int r = i >> 4, c = i & 15;
        uint4 v = make_uint4(0, 0, 0, 0);
        int row = M0 + r;
        if (row < M) v = *(const uint4*)&A[(size_t)row * K + c * 8];
        *(uint4*)&As[r * stride + c * 8] = v;
    }
    __syncthreads();

    int wave = tid >> 6, lane = tid & 63;
    const halfx8* bu = (const halfx8*)WpU + (size_t)wave * steps * 64 + lane;
    const halfx8* bv = (const halfx8*)WpV + (size_t)wave * steps * 64 + lane;
    const _Float16* arow = &As[(lane & 31) * stride + ((lane >> 5) << 3)];
    f32x16 au = {}, av = {};
#pragma unroll
    for (int s = 0; s < steps; s++) {
        halfx8 a = *(const halfx8*)&arow[s * 16];
        au = __builtin_amdgcn_mfma_f32_32x32x16_f16(a, bu[s * 64], au, 0, 0, 0);
        av = __builtin_amdgcn_mfma_f32_32x32x16_f16(a, bv[s * 64], av, 0, 0, 0);
    }
    int col = wave * 32 + (lane & 31);
    float bA = bm1[col];
#pragma unroll
    for (int r = 0; r < 16; r++) {
        int rl = (r & 3) + 8 * (r >> 2) + 4 * (lane >> 5);
        int grow = M0 + rl;
        if (grow < M) {
            U[(size_t)grow * 128 + col] = (_Float16)(au[r] + bA);
            V[(size_t)grow * 128 + col] = (_Float16)av[r];
        }
    }
}

// ---------------------------------------------------------------------------
// GCN aggregation: half-wave per node (32 lanes x 4 cols, 8 B/lane).
// DO NOT fuse into GEMM (R7 lesson: grid collapse kills gather parallelism).
// ---------------------------------------------------------------------------
__global__ __launch_bounds__(256) void aggregate_kernel(const _Float16* __restrict__ y,
                                                        const float* __restrict__ dinv,
                                                        const int* __restrict__ ptr,
                                                        const int* __restrict__ ce_src,
                                                        const float* __restrict__ bias,
                                                        _Float16* __restrict__ out) {
    int node = blockIdx.x * 8 + (threadIdx.x >> 5);
    int l = threadIdx.x & 31;
    float di = dinv[node];
    half4v self = ((const half4v*)&y[(size_t)node * 128])[l];
    float a0 = (float)self[0], a1 = (float)self[1], a2 = (float)self[2], a3 = (float)self[3];
    float b0 = 0.f, b1 = 0.f, b2 = 0.f, b3 = 0.f;
    int s0 = ptr[node], s1 = ptr[node + 1];
    int j = s0;
    for (; j + 7 < s1; j += 8) {
        int n0 = ce_src[j], n1 = ce_src[j + 1], n2 = ce_src[j + 2], n3 = ce_src[j + 3];
        int n4 = ce_src[j + 4], n5 = ce_src[j + 5], n6 = ce_src[j + 6], n7 = ce_src[j + 7];
        half4v v0 = ((const half4v*)&y[(size_t)n0 * 128])[l];
        half4v v1 = ((const half4v*)&y[(size_t)n1 * 128])[l];
        half4v v2 = ((const half4v*)&y[(size_t)n2 * 128])[l];
        half4v v3 = ((const half4v*)&y[(size_t)n3 * 128])[l];
        half4v v4 = ((const half4v*)&y[(size_t)n4 * 128])[l];
        half4v v5 = ((const half4v*)&y[(size_t)n5 * 128])[l];
        half4v v6 = ((const half4v*)&y[(size_t)n6 * 128])[l];
        half4v v7 = ((const half4v*)&y[(size_t)n7 * 128])[l];
        a0 += (float)v0[0] + (float)v2[0] + (float)v4[0] + (float)v6[0];
        a1 += (float)v0[1] + (float)v2[1] + (float)v4[1] + (float)v6[1];
        a2 += (float)v0[2] + (float)v2[2] + (float)v4[2] + (float)v6[2];
        a3 += (float)v0[3] + (float)v2[3] + (float)v4[3] + (float)v6[3];
        b0 += (float)v1[0] + (float)v3[0] + (float)v5[0] + (float)v7[0];
        b1 += (float)v1[1] + (float)v3[1] + (float)v5[1] + (float)v7[1];
        b2 += (float)v1[2] + (float)v3[2] + (float)v5[2] + (float)v7[2];
        b3 += (float)v1[3] + (float)v3[3] + (float)v5[3] + (float)v7[3];
    }
    for (; j < s1; j++) {
        int n = ce_src[j];
        half4v v = ((const half4v*)&y[(size_t)n * 128])[l];
        a0 += (float)v[0]; a1 += (float)v[1]; a2 += (float)v[2]; a3 += (float)v[3];
    }
    float4 bv = *(const float4*)&bias[l * 4];
    half4v ov;
    ov[0] = (_Float16)fmaxf(di * (a0 + b0) + bv.x, 0.f);
    ov[1] = (_Float16)fmaxf(di * (a1 + b1) + bv.y, 0.f);
    ov[2] = (_Float16)fmaxf(di * (a2 + b2) + bv.z, 0.f);
    ov[3] = (_Float16)fmaxf(di * (a3 + b3) + bv.w, 0.f);
    ((half4v*)&out[(size_t)node * 128])[l] = ov;
}

// ---------------------------------------------------------------------------
// Edge MLP: 128 edges/block, 8 edges per 16-lane group (16 gathers in
// flight/thread), packed fp16 add+relu + v_dot2_f32_f16 accumulation.
// ---------------------------------------------------------------------------
__global__ __launch_bounds__(256) void edge_mlp_kernel(const _Float16* __restrict__ Ub,
                                                       const _Float16* __restrict__ Vb,
                                                       const int* __restrict__ ce_src,
                                                       const int* __restrict__ ce_eid,
                                                       const int* __restrict__ ce_dst,
                                                       const _Float16* __restrict__ Wm2h,
                                                       const float* __restrict__ bm2,
                                                       float* __restrict__ out) {
    __shared__ int ssrc[128], sdst[128], seid[128];
    int tid = threadIdx.x;
    int e0 = blockIdx.x * 128;
    if (tid < 128) {
        ssrc[tid] = ce_src[e0 + tid];
        seid[tid] = ce_eid[e0 + tid];
    } else {
        sdst[tid - 128] = ce_dst[e0 + tid - 128];
    }
    __syncthreads();
    int g = tid >> 4;     // group 0..15
    int l = tid & 15;     // cols l*8 .. l*8+7
    halfx8 wv = *(const halfx8*)&Wm2h[l * 8];
    half2v w0 = {wv[0], wv[1]}, w1 = {wv[2], wv[3]}, w2 = {wv[4], wv[5]}, w3 = {wv[6], wv[7]};
    halfx8 uu[8], vv[8];
#pragma unroll
    for (int k = 0; k < 8; k++) {
        int e = g + 16 * k;
        uu[k] = *(const halfx8*)&Ub[(size_t)ssrc[e] * 128 + l * 8];
        vv[k] = *(const halfx8*)&Vb[(size_t)sdst[e] * 128 + l * 8];
    }
    float p[8];
#pragma unroll
    for (int k = 0; k < 8; k++) {
        halfx8 s = relu8(uu[k] + vv[k]);
        half2v s0 = {s[0], s[1]}, s1 = {s[2], s[3]}, s2 = {s[4], s[5]}, s3 = {s[6], s[7]};
        float acc = dot2acc(s0, w0, 0.f);
        acc = dot2acc(s1, w1, acc);
        acc = dot2acc(s2, w2, acc);
        p[k] = dot2acc(s3, w3, acc);
    }
#pragma unroll
    for (int d = 1; d < 16; d <<= 1) {
#pragma unroll
        for (int k = 0; k < 8; k++) p[k] += __shfl_xor(p[k], d);
    }
    if (l == 0) {
        float bb = bm2[0];
#pragma unroll
        for (int k = 0; k < 8; k++) out[seid[g + 16 * k]] = p[k] + bb;
    }
}

// ---------------------------------------------------------------------------
extern "C" void kernel_launch(void* const* d_in, const int* in_sizes, int n_in,
                              void* d_out, int out_size, void* d_ws, size_t ws_size,
                              hipStream_t stream) {
    const float* x    = (const float*)d_in[0];
    const int* eidx   = (const int*)d_in[1];
    const float* W_in = (const float*)d_in[2];
    const float* b_in = (const float*)d_in[3];
    const float* W1   = (const float*)d_in[4];
    const float* b1   = (const float*)d_in[5];
    const float* W2   = (const float*)d_in[6];
    const float* b2   = (const float*)d_in[7];
    const float* Wm1  = (const float*)d_in[8];
    const float* bm1  = (const float*)d_in[9];
    const float* Wm2  = (const float*)d_in[10];
    const float* bm2  = (const float*)d_in[11];
    float* out = (float*)d_out;
    const int* src = eidx;
    const int* dst = eidx + N_EDGES;

    char* w = (char*)d_ws;
    size_t off = 0;
    auto alloc = [&](size_t bytes) -> char* {
        char* p = w + off;
        off = (off + bytes + 255) & ~(size_t)255;
        return p;
    };
    int* bhist    = (int*)alloc((size_t)NB * 4);
    int* boff     = (int*)alloc((size_t)(NB + 1) * 4);
    int* bcursor  = (int*)alloc((size_t)NB * 4);
    int* csr_ptr  = (int*)alloc((size_t)(N_NODES + 1) * 4);
    float* dinv   = (float*)alloc((size_t)N_NODES * 4);
    unsigned long long* binned = (unsigned long long*)alloc((size_t)N_EDGES * 8);
    int* ce_src   = (int*)alloc((size_t)N_EDGES * 4);
    int* ce_eid   = (int*)alloc((size_t)N_EDGES * 4);
    int* ce_dst   = (int*)alloc((size_t)N_EDGES * 4);
    _Float16* Wp  = (_Float16*)alloc((size_t)77952 * 2);
    _Float16* y1  = (_Float16*)alloc((size_t)N_NODES * HID * 2);
    _Float16* y2  = (_Float16*)alloc((size_t)N_NODES * HID * 2);
    _Float16* hbuf = (_Float16*)alloc((size_t)N_NODES * HID * 2);
    _Float16* Ub  = (_Float16*)alloc((size_t)N_NODES * HID * 2);
    _Float16* Vb  = (_Float16*)alloc((size_t)N_NODES * HID * 2);

    const _Float16* WpIn  = Wp;              // K=96, steps 6
    const _Float16* Wp1   = Wp + 12288;      // K=128
    const _Float16* Wp2   = Wp + 28672;
    const _Float16* WpM1a = Wp + 45056;
    const _Float16* WpM1b = Wp + 61440;
    const _Float16* Wm2h  = Wp + 77824;

    // CSR build (counting sort) + weight pack (merged into pass 1)
    hipMemsetAsync(bhist, 0, (size_t)NB * 4, stream);
    hist_pack_kernel<<<196 + 305, 256, 0, stream>>>(dst, bhist, W_in, W1, W2, Wm1, Wm2, Wp);
    scan_buckets_kernel<<<1, 512, 0, stream>>>(bhist, boff, bcursor);
    bin_kernel<<<98, 512, 0, stream>>>(src, dst, bcursor, binned);
    bucket_sort_kernel<<<NB, 256, 0, stream>>>(binned, boff, ce_src, ce_eid, ce_dst,
                                               csr_ptr, dinv);

    int gblocks = (N_NODES + 31) / 32;  // 1563
    // y1 = (relu(x@W_in+b_in) @ W1) * dinv          (h0 LDS-only)
    fused_in_kernel<<<gblocks, 256, 0, stream>>>(x, WpIn, Wp1, b_in, dinv, y1, N_NODES);
    // h1 = relu(dinv*(y1_self + sum y1[src]) + b1)  -> hbuf
    aggregate_kernel<<<N_NODES / 8, 256, 0, stream>>>(y1, dinv, csr_ptr, ce_src, b1, hbuf);
    // y2 = (h1 @ W2) * dinv                         -> y2
    gemm_f16_kernel<<<gblocks, 256, 0, stream>>>(hbuf, Wp2, nullptr, dinv, y2,
                                                 N_NODES, HID, 8, 0);
    // h2 = relu(dinv*(y2_self + sum y2[src]) + b2)  -> hbuf
    aggregate_kernel<<<N_NODES / 8, 256, 0, stream>>>(y2, dinv, csr_ptr, ce_src, b2, hbuf);
    // U = h2@Wm1a+bm1, V = h2@Wm1b                  -> Ub, Vb
    gemm_uv_kernel<<<gblocks, 256, 0, stream>>>(hbuf, WpM1a, WpM1b, bm1, Ub, Vb, N_NODES);
    // logits (CSR order, scatter by original edge id)
    edge_mlp_kernel<<<N_EDGES / 128, 256, 0, stream>>>(Ub, Vb, ce_src, ce_eid, ce_dst,
                                                       Wm2h, bm2, out);
}